// Round 5
// baseline (2193.886 us; speedup 1.0000x reference)
//
#include <hip/hip_runtime.h>
#include <hip/hip_bf16.h>
#include <math.h>

#define BQ 32
#define SQ 197
#define EQ 768
#define HQ 12
#define DHQ 64
#define FQ 2048
#define LQ 4
#define CQ 1000
#define BSQ (BQ*SQ)     // 6304
#define MPAD 6400       // 6304 padded to 128-multiple for MFMA A-tiles
#define QKV3 2304       // fused q|k|v row width
#define TPAD 256        // attention t-dim padded
#define LN_EPS 1e-5f

typedef __bf16 bf16x8 __attribute__((ext_vector_type(8)));
typedef float f32x4 __attribute__((ext_vector_type(4)));

__device__ __forceinline__ __hip_bfloat16 tobf(float f) { return __float2bfloat16(f); }

// ---------------- transpose + fp32->bf16 convert: out[c][r] = in[r][c] ------
__global__ __launch_bounds__(256) void tconv(const float* __restrict__ in,
    __hip_bfloat16* __restrict__ out, int R, int C, size_t slab)
{
    __shared__ float tile[64][65];
    const float* ip = in + (size_t)blockIdx.z * slab;
    __hip_bfloat16* op = out + (size_t)blockIdx.z * slab;
    int r0 = blockIdx.x * 64, c0 = blockIdx.y * 64;
    int t = threadIdx.x;
    int tc = t & 63, tr = t >> 6;
    #pragma unroll
    for (int p = 0; p < 16; ++p) {
        int r = p * 4 + tr;
        tile[r][tc] = ip[(size_t)(r0 + r) * C + c0 + tc];
    }
    __syncthreads();
    #pragma unroll
    for (int p = 0; p < 16; ++p) {
        int c = p * 4 + tr;
        op[(size_t)(c0 + c) * R + r0 + tc] = tobf(tile[tc][c]);
    }
}

// ---------------- LayerNorm: fp32 in -> bf16 out ----------------------------
__global__ __launch_bounds__(256) void ln_kernel(const float* __restrict__ in,
    const float* __restrict__ w, const float* __restrict__ b,
    __hip_bfloat16* __restrict__ out)
{
    int row = blockIdx.x;
    const float* x = in + (size_t)row * EQ;
    int t = threadIdx.x;
    float v0 = x[t];
    float v1 = x[t + 256];
    float v2 = x[t + 512];
    __shared__ float red[256];
    red[t] = v0 + v1 + v2;
    __syncthreads();
    for (int off = 128; off > 0; off >>= 1) {
        if (t < off) red[t] += red[t + off];
        __syncthreads();
    }
    float mu = red[0] * (1.0f / EQ);
    __syncthreads();
    float d0 = v0 - mu, d1 = v1 - mu, d2 = v2 - mu;
    red[t] = d0*d0 + d1*d1 + d2*d2;
    __syncthreads();
    for (int off = 128; off > 0; off >>= 1) {
        if (t < off) red[t] += red[t + off];
        __syncthreads();
    }
    float rs = rsqrtf(red[0] * (1.0f / EQ) + LN_EPS);
    __hip_bfloat16* o = out + (size_t)row * EQ;
    o[t]       = tobf(d0 * rs * w[t]       + b[t]);
    o[t + 256] = tobf(d1 * rs * w[t + 256] + b[t + 256]);
    o[t + 512] = tobf(d2 * rs * w[t + 512] + b[t + 512]);
}

// ---------------- bf16 MFMA GEMM: C = A(MxK) @ Bt(NxK)^T --------------------
// NO LDS, NO barriers: every wave loads its MFMA fragments directly from
// global to VGPRs. The k-loop is a pure global_load <-> mfma dataflow the
// compiler pipelines with fine-grained vmcnt (AITER-style), instead of the
// barrier+vmcnt(0) drain that capped the staged version at ~10% MfmaUtil.
// Tile: (IM*32) x 128 with 4 waves in 2x2; wave tile (IM*16) x 64.
enum { EPI_NONE = 0, EPI_RES = 1, EPI_BIAS_GELU = 2, EPI_BIAS_RES = 3 };

template<int EPI, bool OUTBF16, int IM>
__global__ __launch_bounds__(256) void mgemm(
    const unsigned short* __restrict__ A, const unsigned short* __restrict__ Bt,
    void* __restrict__ Cm, const float* __restrict__ bias,
    const float* __restrict__ res, int M, int N, int K)
{
    const int tid = threadIdx.x;
    const int lane = tid & 63;
    const int w = tid >> 6;
    const int wr = w >> 1, wc = w & 1;
    const int l15 = lane & 15, quad = lane >> 4;
    const int row0 = blockIdx.x * (IM * 32), col0 = blockIdx.y * 128;

    // lane-fixed base pointers; k advances by +k0, i/j by +16*K
    const unsigned short* Ap = A + (size_t)(row0 + wr * (IM * 16) + l15) * K + quad * 8;
    const unsigned short* Bp = Bt + (size_t)(col0 + wc * 64 + l15) * K + quad * 8;

    f32x4 acc[IM][4] = {};

    #pragma unroll 4
    for (int k0 = 0; k0 < K; k0 += 32) {
        bf16x8 af[IM], bfr[4];
        #pragma unroll
        for (int i = 0; i < IM; ++i)
            af[i] = *(const bf16x8*)(Ap + (size_t)i * 16 * K + k0);
        #pragma unroll
        for (int j = 0; j < 4; ++j)
            bfr[j] = *(const bf16x8*)(Bp + (size_t)j * 16 * K + k0);
        #pragma unroll
        for (int i = 0; i < IM; ++i)
            #pragma unroll
            for (int j = 0; j < 4; ++j)
                acc[i][j] = __builtin_amdgcn_mfma_f32_16x16x32_bf16(af[i], bfr[j], acc[i][j], 0, 0, 0);
    }

    #pragma unroll
    for (int j = 0; j < 4; ++j) {
        int c = col0 + wc * 64 + j * 16 + l15;
        float bv = 0.f;
        if (EPI == EPI_BIAS_GELU || EPI == EPI_BIAS_RES) bv = bias[c];
        #pragma unroll
        for (int i = 0; i < IM; ++i) {
            #pragma unroll
            for (int rg = 0; rg < 4; ++rg) {
                int r = row0 + wr * (IM * 16) + i * 16 + quad * 4 + rg;
                if (r < M) {
                    float v = acc[i][j][rg];
                    size_t idx = (size_t)r * N + c;
                    if (EPI == EPI_RES) {
                        v += res[idx];
                    } else if (EPI == EPI_BIAS_GELU) {
                        v += bv;
                        v = 0.5f * v * (1.0f + erff(v * 0.70710678118654752f));
                    } else if (EPI == EPI_BIAS_RES) {
                        v += bv + res[idx];
                    }
                    if (OUTBF16) ((__hip_bfloat16*)Cm)[idx] = tobf(v);
                    else         ((float*)Cm)[idx] = v;
                }
            }
        }
    }
}

// ------------- fused scores+softmax: per (s-tile, bh) block -----------------
__global__ __launch_bounds__(256) void attn_sm(
    const unsigned short* __restrict__ qkv, unsigned short* __restrict__ att)
{
    const int s0 = blockIdx.x * 64;
    const int bh = blockIdx.y;
    const int b = bh / HQ, h = bh % HQ;
    const int tid = threadIdx.x;
    const int w = tid >> 6;
    const int lane = tid & 63;
    const int l15 = lane & 15, quad = lane >> 4;
    __shared__ float redm[4][64], reds[4][64];

    const size_t qbase = ((size_t)b * SQ) * QKV3 + h * DHQ;
    const size_t kbase = qbase + EQ;

    f32x4 acc[4][4] = {};
    #pragma unroll
    for (int ks = 0; ks < 2; ++ks) {
        bf16x8 af[4], bfr[4];
        #pragma unroll
        for (int i = 0; i < 4; ++i)
            af[i] = *(const bf16x8*)(qkv + qbase + (size_t)(s0 + i * 16 + l15) * QKV3 + ks * 32 + quad * 8);
        #pragma unroll
        for (int j = 0; j < 4; ++j)
            bfr[j] = *(const bf16x8*)(qkv + kbase + (size_t)(w * 64 + j * 16 + l15) * QKV3 + ks * 32 + quad * 8);
        #pragma unroll
        for (int i = 0; i < 4; ++i)
            #pragma unroll
            for (int j = 0; j < 4; ++j)
                acc[i][j] = __builtin_amdgcn_mfma_f32_16x16x32_bf16(af[i], bfr[j], acc[i][j], 0, 0, 0);
    }

    const float scale = 0.07124704998790965f;  // 1/sqrt(197)
    float sc[4][4][4];
    #pragma unroll
    for (int i = 0; i < 4; ++i)
        #pragma unroll
        for (int j = 0; j < 4; ++j) {
            bool ok = (w * 64 + j * 16 + l15) < SQ;
            #pragma unroll
            for (int rg = 0; rg < 4; ++rg)
                sc[i][rg][j] = ok ? acc[i][j][rg] * scale : -1e30f;
        }

    #pragma unroll
    for (int i = 0; i < 4; ++i)
        #pragma unroll
        for (int rg = 0; rg < 4; ++rg) {
            float m = fmaxf(fmaxf(sc[i][rg][0], sc[i][rg][1]), fmaxf(sc[i][rg][2], sc[i][rg][3]));
            #pragma unroll
            for (int d = 1; d < 16; d <<= 1) m = fmaxf(m, __shfl_xor(m, d));
            if (l15 == 0) redm[w][i * 16 + quad * 4 + rg] = m;
        }
    __syncthreads();

    float tot[4][4];
    #pragma unroll
    for (int i = 0; i < 4; ++i)
        #pragma unroll
        for (int rg = 0; rg < 4; ++rg) {
            int row = i * 16 + quad * 4 + rg;
            float m = fmaxf(fmaxf(redm[0][row], redm[1][row]),
                            fmaxf(redm[2][row], redm[3][row]));
            float s = 0.f;
            #pragma unroll
            for (int j = 0; j < 4; ++j) {
                float e = expf(sc[i][rg][j] - m);
                sc[i][rg][j] = e;
                s += e;
            }
            #pragma unroll
            for (int d = 1; d < 16; d <<= 1) s += __shfl_xor(s, d);
            if (l15 == 0) reds[w][row] = s;
            tot[i][rg] = 0.f;
        }
    __syncthreads();

    #pragma unroll
    for (int i = 0; i < 4; ++i)
        #pragma unroll
        for (int rg = 0; rg < 4; ++rg) {
            int row = i * 16 + quad * 4 + rg;
            tot[i][rg] = reds[0][row] + reds[1][row] + reds[2][row] + reds[3][row];
        }

    #pragma unroll
    for (int i = 0; i < 4; ++i)
        #pragma unroll
        for (int rg = 0; rg < 4; ++rg) {
            int srow = s0 + i * 16 + quad * 4 + rg;
            if (srow < SQ) {
                float inv = 1.0f / tot[i][rg];
                __hip_bfloat16* ap = (__hip_bfloat16*)att +
                    ((size_t)bh * SQ + srow) * TPAD + w * 64 + l15;
                #pragma unroll
                for (int j = 0; j < 4; ++j)
                    ap[j * 16] = tobf(sc[i][rg][j] * inv);
            }
        }
}

// ------------- o = att @ v : per (s-tile, bh) block, V^T staged in LDS ------
__global__ __launch_bounds__(256) void attv_mfma(
    const unsigned short* __restrict__ att, const unsigned short* __restrict__ qkv,
    __hip_bfloat16* __restrict__ o)
{
    __shared__ unsigned short Vs[64][264];
    const int s0 = blockIdx.x * 64;
    const int bh = blockIdx.y;
    const int b = bh / HQ, h = bh % HQ;
    const int tid = threadIdx.x;
    const int w = tid >> 6, lane = tid & 63;
    const int wr = w >> 1, wc = w & 1;
    const int l15 = lane & 15, quad = lane >> 4;

    const size_t vbase = ((size_t)b * SQ) * QKV3 + 2 * EQ + h * DHQ;
    {
        int t = tid;
        #pragma unroll
        for (int dch = 0; dch < 16; ++dch) {
            ushort4 u = *(const ushort4*)(qkv + vbase + (size_t)t * QKV3 + dch * 4);
            Vs[dch * 4 + 0][t] = u.x;
            Vs[dch * 4 + 1][t] = u.y;
            Vs[dch * 4 + 2][t] = u.z;
            Vs[dch * 4 + 3][t] = u.w;
        }
    }
    __syncthreads();

    const size_t arow = (size_t)bh * SQ + s0;
    f32x4 acc[2][2] = {};
    #pragma unroll
    for (int ks = 0; ks < 8; ++ks) {
        bf16x8 af[2], bfr[2];
        #pragma unroll
        for (int i = 0; i < 2; ++i)
            af[i] = *(const bf16x8*)(att + (arow + wr * 32 + i * 16 + l15) * TPAD + ks * 32 + quad * 8);
        #pragma unroll
        for (int j = 0; j < 2; ++j)
            bfr[j] = *(const bf16x8*)&Vs[wc * 32 + j * 16 + l15][ks * 32 + quad * 8];
        #pragma unroll
        for (int i = 0; i < 2; ++i)
            #pragma unroll
            for (int j = 0; j < 2; ++j)
                acc[i][j] = __builtin_amdgcn_mfma_f32_16x16x32_bf16(af[i], bfr[j], acc[i][j], 0, 0, 0);
    }

    #pragma unroll
    for (int i = 0; i < 2; ++i)
        #pragma unroll
        for (int rg = 0; rg < 4; ++rg) {
            int srow = s0 + wr * 32 + i * 16 + quad * 4 + rg;
            if (srow < SQ) {
                __hip_bfloat16* op = o + ((size_t)b * SQ + srow) * EQ + h * DHQ + wc * 32 + l15;
                #pragma unroll
                for (int j = 0; j < 2; ++j)
                    op[j * 16] = tobf(acc[i][j][rg]);
            }
        }
}

// ---------------- classifier: logits GEMV (parallel) + softmax --------------
__global__ __launch_bounds__(256) void logits_kernel(
    const float* __restrict__ hbuf, const float* __restrict__ Wc,
    const float* __restrict__ bc, float* __restrict__ logits)
{
    __shared__ __align__(16) float hs[768];
    int b = blockIdx.y;
    int c = blockIdx.x * 256 + threadIdx.x;
    const float* hr = hbuf + (size_t)b * SQ * EQ;
    for (int p = threadIdx.x; p < 192; p += 256)
        *(float4*)&hs[p << 2] = *(const float4*)(hr + (p << 2));
    __syncthreads();
    if (c < CQ) {
        float s = bc[c];
        #pragma unroll 8
        for (int e = 0; e < EQ; ++e)
            s = fmaf(hs[e], Wc[(size_t)e * CQ + c], s);
        logits[(size_t)b * CQ + c] = s;
    }
}

__global__ __launch_bounds__(256) void smax_kernel(
    const float* __restrict__ logits, float* __restrict__ out)
{
    __shared__ float red[256];
    int b = blockIdx.x;
    int t = threadIdx.x;
    const float* lp = logits + (size_t)b * CQ;
    float lg[4];
    #pragma unroll
    for (int j = 0; j < 4; ++j) {
        int c = t + j * 256;
        lg[j] = (c < CQ) ? lp[c] : -1e30f;
    }
    float m = fmaxf(fmaxf(lg[0], lg[1]), fmaxf(lg[2], lg[3]));
    red[t] = m;
    __syncthreads();
    for (int off = 128; off; off >>= 1) {
        if (t < off) red[t] = fmaxf(red[t], red[t + off]);
        __syncthreads();
    }
    m = red[0];
    __syncthreads();
    float ex[4], s = 0.f;
    #pragma unroll
    for (int j = 0; j < 4; ++j) {
        ex[j] = (t + j * 256 < CQ) ? expf(lg[j] - m) : 0.f;
        s += ex[j];
    }
    red[t] = s;
    __syncthreads();
    for (int off = 128; off; off >>= 1) {
        if (t < off) red[t] += red[t + off];
        __syncthreads();
    }
    float inv = 1.0f / red[0];
    #pragma unroll
    for (int j = 0; j < 4; ++j)
        if (t + j * 256 < CQ) out[(size_t)b * CQ + t + j * 256] = ex[j] * inv;
}

extern "C" void kernel_launch(void* const* d_in, const int* in_sizes, int n_in,
                              void* d_out, int out_size, void* d_ws, size_t ws_size,
                              hipStream_t stream)
{
    const float* x     = (const float*)d_in[0];
    const float* Wk    = (const float*)d_in[1];
    const float* Wq    = (const float*)d_in[2];
    const float* Wv    = (const float*)d_in[3];
    const float* Wconv = (const float*)d_in[4];
    const float* ln1w  = (const float*)d_in[5];
    const float* ln1b  = (const float*)d_in[6];
    const float* ln2w  = (const float*)d_in[7];
    const float* ln2b  = (const float*)d_in[8];
    const float* W1    = (const float*)d_in[9];
    const float* b1    = (const float*)d_in[10];
    const float* W2    = (const float*)d_in[11];
    const float* b2    = (const float*)d_in[12];
    const float* Wc    = (const float*)d_in[13];
    const float* bc    = (const float*)d_in[14];
    float* out = (float*)d_out;

    const size_t BSE   = (size_t)BSQ * EQ;
    const size_t ATTR  = (size_t)BQ * HQ * SQ + 64;

    float* w = (float*)d_ws;
    float* bh    = w; w += BSE;
    float* res1  = w; w += BSE;
    float* logit = w; w += (size_t)BQ * CQ;
    __hip_bfloat16* qkvbf = (__hip_bfloat16*)w; w += (size_t)MPAD * QKV3 / 2;
    __hip_bfloat16* actb  = (__hip_bfloat16*)w; w += (size_t)MPAD * EQ / 2;
    __hip_bfloat16* attbf = (__hip_bfloat16*)w; w += ATTR * TPAD / 2;
    __hip_bfloat16* wbuf  = (__hip_bfloat16*)w;
    __hip_bfloat16* ffh   = attbf;

    const size_t WQKV = (size_t)EQ * EQ;
    __hip_bfloat16* WqT = wbuf;
    __hip_bfloat16* WkT = wbuf + WQKV;
    __hip_bfloat16* WvT = wbuf + 2 * WQKV;
    __hip_bfloat16* WcvT = wbuf;
    __hip_bfloat16* W1T  = wbuf + WQKV;
    __hip_bfloat16* W2T  = W1T + (size_t)EQ * FQ;

    for (int l = 0; l < LQ; ++l) {
        const float* hin = (l == 0) ? x : bh;
        tconv<<<dim3(12, 1, HQ), 256, 0, stream>>>(Wq + (size_t)l * HQ * EQ * DHQ, WqT, EQ, DHQ, (size_t)EQ * DHQ);
        tconv<<<dim3(12, 1, HQ), 256, 0, stream>>>(Wk + (size_t)l * HQ * EQ * DHQ, WkT, EQ, DHQ, (size_t)EQ * DHQ);
        tconv<<<dim3(12, 1, HQ), 256, 0, stream>>>(Wv + (size_t)l * HQ * EQ * DHQ, WvT, EQ, DHQ, (size_t)EQ * DHQ);

        ln_kernel<<<BSQ, 256, 0, stream>>>(hin, ln1w + l * EQ, ln1b + l * EQ, actb);

        mgemm<EPI_NONE, true, 4><<<dim3(50, 18), 256, 0, stream>>>(
            (const unsigned short*)actb, (const unsigned short*)WqT, qkvbf, nullptr, nullptr, BSQ, QKV3, EQ);

        tconv<<<dim3(12, 12, 1), 256, 0, stream>>>(Wconv + (size_t)l * EQ * EQ, WcvT, EQ, EQ, 0);
        tconv<<<dim3(12, 32, 1), 256, 0, stream>>>(W1 + (size_t)l * EQ * FQ, W1T, EQ, FQ, 0);
        tconv<<<dim3(32, 12, 1), 256, 0, stream>>>(W2 + (size_t)l * FQ * EQ, W2T, FQ, EQ, 0);

        attn_sm<<<dim3(4, BQ * HQ), 256, 0, stream>>>((const unsigned short*)qkvbf, (unsigned short*)attbf);
        attv_mfma<<<dim3(4, BQ * HQ), 256, 0, stream>>>((const unsigned short*)attbf, (const unsigned short*)qkvbf, actb);

        mgemm<EPI_RES, false, 2><<<dim3(100, 6), 256, 0, stream>>>(
            (const unsigned short*)actb, (const unsigned short*)WcvT, res1, nullptr, hin, BSQ, EQ, EQ);

        ln_kernel<<<BSQ, 256, 0, stream>>>(res1, ln2w + l * EQ, ln2b + l * EQ, actb);

        mgemm<EPI_BIAS_GELU, true, 4><<<dim3(50, 16), 256, 0, stream>>>(
            (const unsigned short*)actb, (const unsigned short*)W1T, ffh, b1 + l * FQ, nullptr, BSQ, FQ, EQ);
        mgemm<EPI_BIAS_RES, false, 2><<<dim3(100, 6), 256, 0, stream>>>(
            (const unsigned short*)ffh, (const unsigned short*)W2T, bh, b2 + l * EQ, res1, BSQ, EQ, FQ);
    }
    logits_kernel<<<dim3(4, BQ), 256, 0, stream>>>(bh, Wc, bc, logit);
    smax_kernel<<<BQ, 256, 0, stream>>>(logit, out);
}

// Round 6
// 1376.838 us; speedup vs baseline: 1.5934x; 1.5934x over previous
//
#include <hip/hip_runtime.h>
#include <hip/hip_bf16.h>
#include <math.h>

#define BQ 32
#define SQ 197
#define EQ 768
#define HQ 12
#define DHQ 64
#define FQ 2048
#define LQ 4
#define CQ 1000
#define BSQ (BQ*SQ)     // 6304
#define MPAD 6400       // 6304 padded to 128-multiple for MFMA A-tiles
#define QKV3 2304       // fused q|k|v row width
#define TPAD 256        // attention t-dim padded
#define LN_EPS 1e-5f

typedef __bf16 bf16x8 __attribute__((ext_vector_type(8)));
typedef float f32x4 __attribute__((ext_vector_type(4)));
typedef unsigned short u16x8 __attribute__((ext_vector_type(8)));

__device__ __forceinline__ __hip_bfloat16 tobf(float f) { return __float2bfloat16(f); }

// ---------------- transpose + fp32->bf16 convert: out[c][r] = in[r][c] ------
__global__ __launch_bounds__(256) void tconv(const float* __restrict__ in,
    __hip_bfloat16* __restrict__ out, int R, int C, size_t slab)
{
    __shared__ float tile[64][65];
    const float* ip = in + (size_t)blockIdx.z * slab;
    __hip_bfloat16* op = out + (size_t)blockIdx.z * slab;
    int r0 = blockIdx.x * 64, c0 = blockIdx.y * 64;
    int t = threadIdx.x;
    int tc = t & 63, tr = t >> 6;
    #pragma unroll
    for (int p = 0; p < 16; ++p) {
        int r = p * 4 + tr;
        tile[r][tc] = ip[(size_t)(r0 + r) * C + c0 + tc];
    }
    __syncthreads();
    #pragma unroll
    for (int p = 0; p < 16; ++p) {
        int c = p * 4 + tr;
        op[(size_t)(c0 + c) * R + r0 + tc] = tobf(tile[tc][c]);
    }
}

// ---------------- LayerNorm: fp32 in -> bf16 out ----------------------------
__global__ __launch_bounds__(256) void ln_kernel(const float* __restrict__ in,
    const float* __restrict__ w, const float* __restrict__ b,
    __hip_bfloat16* __restrict__ out)
{
    int row = blockIdx.x;
    const float* x = in + (size_t)row * EQ;
    int t = threadIdx.x;
    float v0 = x[t];
    float v1 = x[t + 256];
    float v2 = x[t + 512];
    __shared__ float red[256];
    red[t] = v0 + v1 + v2;
    __syncthreads();
    for (int off = 128; off > 0; off >>= 1) {
        if (t < off) red[t] += red[t + off];
        __syncthreads();
    }
    float mu = red[0] * (1.0f / EQ);
    __syncthreads();
    float d0 = v0 - mu, d1 = v1 - mu, d2 = v2 - mu;
    red[t] = d0*d0 + d1*d1 + d2*d2;
    __syncthreads();
    for (int off = 128; off > 0; off >>= 1) {
        if (t < off) red[t] += red[t + off];
        __syncthreads();
    }
    float rs = rsqrtf(red[0] * (1.0f / EQ) + LN_EPS);
    __hip_bfloat16* o = out + (size_t)row * EQ;
    o[t]       = tobf(d0 * rs * w[t]       + b[t]);
    o[t + 256] = tobf(d1 * rs * w[t + 256] + b[t + 256]);
    o[t + 512] = tobf(d2 * rs * w[t + 512] + b[t + 512]);
}

// ---------------- bf16 MFMA GEMM: C = A(MxK) @ Bt(NxK)^T --------------------
// Pipelined staging: global->VGPR temps for tile k+1 issued BEFORE compute of
// tile k (coalesced 16B/lane), ds_write into the other LDS buffer AFTER
// compute (vmcnt wait lands post-compute => load latency hidden), one barrier
// per iter (lgkm only). XOR-swizzled slots keep fragment ds_reads conflict-free.
// Tile: TM x 128, 4 waves; TM=128 -> wave 64x64, TM=64 -> wave 32x64.
enum { EPI_NONE = 0, EPI_RES = 1, EPI_BIAS_GELU = 2, EPI_BIAS_RES = 3 };

template<int EPI, bool OUTBF16, int TM>
__global__ __launch_bounds__(256) void mgemm(
    const unsigned short* __restrict__ A, const unsigned short* __restrict__ Bt,
    void* __restrict__ Cm, const float* __restrict__ bias,
    const float* __restrict__ res, int M, int N, int K)
{
    constexpr int AC = TM / 64;          // A 16B-chunks per thread (2 or 1)
    constexpr int IM = TM / 32;          // MFMA row-frags per wave (4 or 2)
    __shared__ __align__(16) unsigned short As[2][TM * 32];
    __shared__ __align__(16) unsigned short Bs[2][128 * 32];
    const int tid = threadIdx.x;
    const int lane = tid & 63;
    const int w = tid >> 6;
    const int wr = w >> 1, wc = w & 1;
    const int l15 = lane & 15, quad = lane >> 4;
    const int row0 = blockIdx.x * TM, col0 = blockIdx.y * 128;

    // per-thread staging coords: chunk id = c*256+tid -> row = id>>2, q = id&3
    const int q = tid & 3;

    u16x8 ta[AC], tb[2];
    auto gload = [&](int k0) {
        #pragma unroll
        for (int c = 0; c < AC; ++c) {
            int row = (c * 256 + tid) >> 2;
            ta[c] = *(const u16x8*)(A + (size_t)(row0 + row) * K + k0 + q * 8);
        }
        #pragma unroll
        for (int c = 0; c < 2; ++c) {
            int row = (c * 256 + tid) >> 2;
            tb[c] = *(const u16x8*)(Bt + (size_t)(col0 + row) * K + k0 + q * 8);
        }
    };
    auto swrite = [&](int buf) {
        #pragma unroll
        for (int c = 0; c < AC; ++c) {
            int row = (c * 256 + tid) >> 2;
            int slot = (q + (row >> 1)) & 3;
            *(u16x8*)&As[buf][row * 32 + slot * 8] = ta[c];
        }
        #pragma unroll
        for (int c = 0; c < 2; ++c) {
            int row = (c * 256 + tid) >> 2;
            int slot = (q + (row >> 1)) & 3;
            *(u16x8*)&Bs[buf][row * 32 + slot * 8] = tb[c];
        }
    };

    f32x4 acc[IM][4] = {};
    const int nk = K >> 5;
    gload(0);
    swrite(0);
    __syncthreads();
    int cur = 0;
    for (int k = 0; k < nk; ++k) {
        if (k + 1 < nk) gload((k + 1) << 5);       // coalesced, in flight over compute
        bf16x8 af[IM], bfr[4];
        #pragma unroll
        for (int i = 0; i < IM; ++i) {
            int r = wr * (IM * 16) + i * 16 + l15;
            int slot = (quad + (r >> 1)) & 3;
            af[i] = *(const bf16x8*)&As[cur][r * 32 + slot * 8];
        }
        #pragma unroll
        for (int j = 0; j < 4; ++j) {
            int r = wc * 64 + j * 16 + l15;
            int slot = (quad + (r >> 1)) & 3;
            bfr[j] = *(const bf16x8*)&Bs[cur][r * 32 + slot * 8];
        }
        #pragma unroll
        for (int i = 0; i < IM; ++i)
            #pragma unroll
            for (int j = 0; j < 4; ++j)
                acc[i][j] = __builtin_amdgcn_mfma_f32_16x16x32_bf16(af[i], bfr[j], acc[i][j], 0, 0, 0);
        if (k + 1 < nk) swrite(cur ^ 1);           // vmcnt wait sits here, post-compute
        __syncthreads();                           // lgkm only: ds_writes visible
        cur ^= 1;
    }

    #pragma unroll
    for (int j = 0; j < 4; ++j) {
        int c = col0 + wc * 64 + j * 16 + l15;
        float bv = 0.f;
        if (EPI == EPI_BIAS_GELU || EPI == EPI_BIAS_RES) bv = bias[c];
        #pragma unroll
        for (int i = 0; i < IM; ++i) {
            #pragma unroll
            for (int rg = 0; rg < 4; ++rg) {
                int r = row0 + wr * (IM * 16) + i * 16 + quad * 4 + rg;
                if (r < M) {
                    float v = acc[i][j][rg];
                    size_t idx = (size_t)r * N + c;
                    if (EPI == EPI_RES) {
                        v += res[idx];
                    } else if (EPI == EPI_BIAS_GELU) {
                        v += bv;
                        v = 0.5f * v * (1.0f + erff(v * 0.70710678118654752f));
                    } else if (EPI == EPI_BIAS_RES) {
                        v += bv + res[idx];
                    }
                    if (OUTBF16) ((__hip_bfloat16*)Cm)[idx] = tobf(v);
                    else         ((float*)Cm)[idx] = v;
                }
            }
        }
    }
}

// ------------- fused scores+softmax: per (s-tile, bh) block -----------------
__global__ __launch_bounds__(256) void attn_sm(
    const unsigned short* __restrict__ qkv, unsigned short* __restrict__ att)
{
    const int s0 = blockIdx.x * 64;
    const int bh = blockIdx.y;
    const int b = bh / HQ, h = bh % HQ;
    const int tid = threadIdx.x;
    const int w = tid >> 6;
    const int lane = tid & 63;
    const int l15 = lane & 15, quad = lane >> 4;
    __shared__ float redm[4][64], reds[4][64];

    const size_t qbase = ((size_t)b * SQ) * QKV3 + h * DHQ;
    const size_t kbase = qbase + EQ;

    f32x4 acc[4][4] = {};
    #pragma unroll
    for (int ks = 0; ks < 2; ++ks) {
        bf16x8 af[4], bfr[4];
        #pragma unroll
        for (int i = 0; i < 4; ++i)
            af[i] = *(const bf16x8*)(qkv + qbase + (size_t)(s0 + i * 16 + l15) * QKV3 + ks * 32 + quad * 8);
        #pragma unroll
        for (int j = 0; j < 4; ++j)
            bfr[j] = *(const bf16x8*)(qkv + kbase + (size_t)(w * 64 + j * 16 + l15) * QKV3 + ks * 32 + quad * 8);
        #pragma unroll
        for (int i = 0; i < 4; ++i)
            #pragma unroll
            for (int j = 0; j < 4; ++j)
                acc[i][j] = __builtin_amdgcn_mfma_f32_16x16x32_bf16(af[i], bfr[j], acc[i][j], 0, 0, 0);
    }

    const float scale = 0.07124704998790965f;  // 1/sqrt(197)
    float sc[4][4][4];
    #pragma unroll
    for (int i = 0; i < 4; ++i)
        #pragma unroll
        for (int j = 0; j < 4; ++j) {
            bool ok = (w * 64 + j * 16 + l15) < SQ;
            #pragma unroll
            for (int rg = 0; rg < 4; ++rg)
                sc[i][rg][j] = ok ? acc[i][j][rg] * scale : -1e30f;
        }

    #pragma unroll
    for (int i = 0; i < 4; ++i)
        #pragma unroll
        for (int rg = 0; rg < 4; ++rg) {
            float m = fmaxf(fmaxf(sc[i][rg][0], sc[i][rg][1]), fmaxf(sc[i][rg][2], sc[i][rg][3]));
            #pragma unroll
            for (int d = 1; d < 16; d <<= 1) m = fmaxf(m, __shfl_xor(m, d));
            if (l15 == 0) redm[w][i * 16 + quad * 4 + rg] = m;
        }
    __syncthreads();

    float tot[4][4];
    #pragma unroll
    for (int i = 0; i < 4; ++i)
        #pragma unroll
        for (int rg = 0; rg < 4; ++rg) {
            int row = i * 16 + quad * 4 + rg;
            float m = fmaxf(fmaxf(redm[0][row], redm[1][row]),
                            fmaxf(redm[2][row], redm[3][row]));
            float s = 0.f;
            #pragma unroll
            for (int j = 0; j < 4; ++j) {
                float e = expf(sc[i][rg][j] - m);
                sc[i][rg][j] = e;
                s += e;
            }
            #pragma unroll
            for (int d = 1; d < 16; d <<= 1) s += __shfl_xor(s, d);
            if (l15 == 0) reds[w][row] = s;
            tot[i][rg] = 0.f;
        }
    __syncthreads();

    #pragma unroll
    for (int i = 0; i < 4; ++i)
        #pragma unroll
        for (int rg = 0; rg < 4; ++rg) {
            int row = i * 16 + quad * 4 + rg;
            tot[i][rg] = reds[0][row] + reds[1][row] + reds[2][row] + reds[3][row];
        }

    #pragma unroll
    for (int i = 0; i < 4; ++i)
        #pragma unroll
        for (int rg = 0; rg < 4; ++rg) {
            int srow = s0 + i * 16 + quad * 4 + rg;
            if (srow < SQ) {
                float inv = 1.0f / tot[i][rg];
                __hip_bfloat16* ap = (__hip_bfloat16*)att +
                    ((size_t)bh * SQ + srow) * TPAD + w * 64 + l15;
                #pragma unroll
                for (int j = 0; j < 4; ++j)
                    ap[j * 16] = tobf(sc[i][rg][j] * inv);
            }
        }
}

// ------------- o = att @ v : per (s-tile, bh) block, V^T staged in LDS ------
__global__ __launch_bounds__(256) void attv_mfma(
    const unsigned short* __restrict__ att, const unsigned short* __restrict__ qkv,
    __hip_bfloat16* __restrict__ o)
{
    __shared__ unsigned short Vs[64][264];
    const int s0 = blockIdx.x * 64;
    const int bh = blockIdx.y;
    const int b = bh / HQ, h = bh % HQ;
    const int tid = threadIdx.x;
    const int w = tid >> 6, lane = tid & 63;
    const int wr = w >> 1, wc = w & 1;
    const int l15 = lane & 15, quad = lane >> 4;

    const size_t vbase = ((size_t)b * SQ) * QKV3 + 2 * EQ + h * DHQ;
    {
        int t = tid;
        #pragma unroll
        for (int dch = 0; dch < 16; ++dch) {
            ushort4 u = *(const ushort4*)(qkv + vbase + (size_t)t * QKV3 + dch * 4);
            Vs[dch * 4 + 0][t] = u.x;
            Vs[dch * 4 + 1][t] = u.y;
            Vs[dch * 4 + 2][t] = u.z;
            Vs[dch * 4 + 3][t] = u.w;
        }
    }
    __syncthreads();

    const size_t arow = (size_t)bh * SQ + s0;
    f32x4 acc[2][2] = {};
    #pragma unroll
    for (int ks = 0; ks < 8; ++ks) {
        bf16x8 af[2], bfr[2];
        #pragma unroll
        for (int i = 0; i < 2; ++i)
            af[i] = *(const bf16x8*)(att + (arow + wr * 32 + i * 16 + l15) * TPAD + ks * 32 + quad * 8);
        #pragma unroll
        for (int j = 0; j < 2; ++j)
            bfr[j] = *(const bf16x8*)&Vs[wc * 32 + j * 16 + l15][ks * 32 + quad * 8];
        #pragma unroll
        for (int i = 0; i < 2; ++i)
            #pragma unroll
            for (int j = 0; j < 2; ++j)
                acc[i][j] = __builtin_amdgcn_mfma_f32_16x16x32_bf16(af[i], bfr[j], acc[i][j], 0, 0, 0);
    }

    #pragma unroll
    for (int i = 0; i < 2; ++i)
        #pragma unroll
        for (int rg = 0; rg < 4; ++rg) {
            int srow = s0 + wr * 32 + i * 16 + quad * 4 + rg;
            if (srow < SQ) {
                __hip_bfloat16* op = o + ((size_t)b * SQ + srow) * EQ + h * DHQ + wc * 32 + l15;
                #pragma unroll
                for (int j = 0; j < 2; ++j)
                    op[j * 16] = tobf(acc[i][j][rg]);
            }
        }
}

// ---------------- classifier: logits GEMV (parallel) + softmax --------------
__global__ __launch_bounds__(256) void logits_kernel(
    const float* __restrict__ hbuf, const float* __restrict__ Wc,
    const float* __restrict__ bc, float* __restrict__ logits)
{
    __shared__ __align__(16) float hs[768];
    int b = blockIdx.y;
    int c = blockIdx.x * 256 + threadIdx.x;
    const float* hr = hbuf + (size_t)b * SQ * EQ;
    for (int p = threadIdx.x; p < 192; p += 256)
        *(float4*)&hs[p << 2] = *(const float4*)(hr + (p << 2));
    __syncthreads();
    if (c < CQ) {
        float s = bc[c];
        #pragma unroll 8
        for (int e = 0; e < EQ; ++e)
            s = fmaf(hs[e], Wc[(size_t)e * CQ + c], s);
        logits[(size_t)b * CQ + c] = s;
    }
}

__global__ __launch_bounds__(256) void smax_kernel(
    const float* __restrict__ logits, float* __restrict__ out)
{
    __shared__ float red[256];
    int b = blockIdx.x;
    int t = threadIdx.x;
    const float* lp = logits + (size_t)b * CQ;
    float lg[4];
    #pragma unroll
    for (int j = 0; j < 4; ++j) {
        int c = t + j * 256;
        lg[j] = (c < CQ) ? lp[c] : -1e30f;
    }
    float m = fmaxf(fmaxf(lg[0], lg[1]), fmaxf(lg[2], lg[3]));
    red[t] = m;
    __syncthreads();
    for (int off = 128; off; off >>= 1) {
        if (t < off) red[t] = fmaxf(red[t], red[t + off]);
        __syncthreads();
    }
    m = red[0];
    __syncthreads();
    float ex[4], s = 0.f;
    #pragma unroll
    for (int j = 0; j < 4; ++j) {
        ex[j] = (t + j * 256 < CQ) ? expf(lg[j] - m) : 0.f;
        s += ex[j];
    }
    red[t] = s;
    __syncthreads();
    for (int off = 128; off; off >>= 1) {
        if (t < off) red[t] += red[t + off];
        __syncthreads();
    }
    float inv = 1.0f / red[0];
    #pragma unroll
    for (int j = 0; j < 4; ++j)
        if (t + j * 256 < CQ) out[(size_t)b * CQ + t + j * 256] = ex[j] * inv;
}

extern "C" void kernel_launch(void* const* d_in, const int* in_sizes, int n_in,
                              void* d_out, int out_size, void* d_ws, size_t ws_size,
                              hipStream_t stream)
{
    const float* x     = (const float*)d_in[0];
    const float* Wk    = (const float*)d_in[1];
    const float* Wq    = (const float*)d_in[2];
    const float* Wv    = (const float*)d_in[3];
    const float* Wconv = (const float*)d_in[4];
    const float* ln1w  = (const float*)d_in[5];
    const float* ln1b  = (const float*)d_in[6];
    const float* ln2w  = (const float*)d_in[7];
    const float* ln2b  = (const float*)d_in[8];
    const float* W1    = (const float*)d_in[9];
    const float* b1    = (const float*)d_in[10];
    const float* W2    = (const float*)d_in[11];
    const float* b2    = (const float*)d_in[12];
    const float* Wc    = (const float*)d_in[13];
    const float* bc    = (const float*)d_in[14];
    float* out = (float*)d_out;

    const size_t BSE   = (size_t)BSQ * EQ;
    const size_t ATTR  = (size_t)BQ * HQ * SQ + 64;

    float* w = (float*)d_ws;
    float* bh    = w; w += BSE;
    float* res1  = w; w += BSE;
    float* logit = w; w += (size_t)BQ * CQ;
    __hip_bfloat16* qkvbf = (__hip_bfloat16*)w; w += (size_t)MPAD * QKV3 / 2;
    __hip_bfloat16* actb  = (__hip_bfloat16*)w; w += (size_t)MPAD * EQ / 2;
    __hip_bfloat16* attbf = (__hip_bfloat16*)w; w += ATTR * TPAD / 2;
    __hip_bfloat16* wbuf  = (__hip_bfloat16*)w;
    __hip_bfloat16* ffh   = attbf;

    const size_t WQKV = (size_t)EQ * EQ;
    __hip_bfloat16* WqT = wbuf;
    __hip_bfloat16* WkT = wbuf + WQKV;
    __hip_bfloat16* WvT = wbuf + 2 * WQKV;
    __hip_bfloat16* WcvT = wbuf;
    __hip_bfloat16* W1T  = wbuf + WQKV;
    __hip_bfloat16* W2T  = W1T + (size_t)EQ * FQ;

    for (int l = 0; l < LQ; ++l) {
        const float* hin = (l == 0) ? x : bh;
        tconv<<<dim3(12, 1, HQ), 256, 0, stream>>>(Wq + (size_t)l * HQ * EQ * DHQ, WqT, EQ, DHQ, (size_t)EQ * DHQ);
        tconv<<<dim3(12, 1, HQ), 256, 0, stream>>>(Wk + (size_t)l * HQ * EQ * DHQ, WkT, EQ, DHQ, (size_t)EQ * DHQ);
        tconv<<<dim3(12, 1, HQ), 256, 0, stream>>>(Wv + (size_t)l * HQ * EQ * DHQ, WvT, EQ, DHQ, (size_t)EQ * DHQ);

        ln_kernel<<<BSQ, 256, 0, stream>>>(hin, ln1w + l * EQ, ln1b + l * EQ, actb);

        mgemm<EPI_NONE, true, 128><<<dim3(50, 18), 256, 0, stream>>>(
            (const unsigned short*)actb, (const unsigned short*)WqT, qkvbf, nullptr, nullptr, BSQ, QKV3, EQ);

        tconv<<<dim3(12, 12, 1), 256, 0, stream>>>(Wconv + (size_t)l * EQ * EQ, WcvT, EQ, EQ, 0);
        tconv<<<dim3(12, 32, 1), 256, 0, stream>>>(W1 + (size_t)l * EQ * FQ, W1T, EQ, FQ, 0);
        tconv<<<dim3(32, 12, 1), 256, 0, stream>>>(W2 + (size_t)l * FQ * EQ, W2T, FQ, EQ, 0);

        attn_sm<<<dim3(4, BQ * HQ), 256, 0, stream>>>((const unsigned short*)qkvbf, (unsigned short*)attbf);
        attv_mfma<<<dim3(4, BQ * HQ), 256, 0, stream>>>((const unsigned short*)attbf, (const unsigned short*)qkvbf, actb);

        mgemm<EPI_RES, false, 64><<<dim3(100, 6), 256, 0, stream>>>(
            (const unsigned short*)actb, (const unsigned short*)WcvT, res1, nullptr, hin, BSQ, EQ, EQ);

        ln_kernel<<<BSQ, 256, 0, stream>>>(res1, ln2w + l * EQ, ln2b + l * EQ, actb);

        mgemm<EPI_BIAS_GELU, true, 128><<<dim3(50, 16), 256, 0, stream>>>(
            (const unsigned short*)actb, (const unsigned short*)W1T, ffh, b1 + l * FQ, nullptr, BSQ, FQ, EQ);
        mgemm<EPI_BIAS_RES, false, 64><<<dim3(100, 6), 256, 0, stream>>>(
            (const unsigned short*)ffh, (const unsigned short*)W2T, bh, b2 + l * EQ, res1, BSQ, EQ, FQ);
    }
    logits_kernel<<<dim3(4, BQ), 256, 0, stream>>>(bh, Wc, bc, logit);
    smax_kernel<<<BQ, 256, 0, stream>>>(logit, out);
}

// Round 7
// 1282.814 us; speedup vs baseline: 1.7102x; 1.0733x over previous
//
#include <hip/hip_runtime.h>
#include <hip/hip_bf16.h>
#include <math.h>

#define BQ 32
#define SQ 197
#define EQ 768
#define HQ 12
#define DHQ 64
#define FQ 2048
#define LQ 4
#define CQ 1000
#define BSQ (BQ*SQ)     // 6304
#define MPAD 6400       // 6304 padded to 128-multiple for MFMA A-tiles
#define QKV3 2304       // fused q|k|v row width
#define TPAD 256        // attention t-dim padded
#define LN_EPS 1e-5f

typedef __bf16 bf16x8 __attribute__((ext_vector_type(8)));
typedef float f32x4 __attribute__((ext_vector_type(4)));
typedef unsigned short u16x8 __attribute__((ext_vector_type(8)));

__device__ __forceinline__ __hip_bfloat16 tobf(float f) { return __float2bfloat16(f); }

// Packed fragment layout: chunk of 8 bf16 for (row-tile rt, k-tile kt, lane):
//   elem = buf[ pk(rt,KT,kt,lane) + e ]  <->  A[rt*16 + (lane&15)][kt*32 + (lane>>4)*8 + e]
// A wave's 64 lanes' chunks are CONSECUTIVE -> one coalesced 1KB load per fragment.
__device__ __forceinline__ size_t pk(int rt, int KT, int kt, int lane) {
    return (((size_t)rt * KT + kt) * 64 + (size_t)lane) * 8;
}

// ---------------- transpose + fp32->bf16 (normal [n][k] layout, for Wconv) --
__global__ __launch_bounds__(256) void tconv(const float* __restrict__ in,
    __hip_bfloat16* __restrict__ out, int R, int C, size_t slab)
{
    __shared__ float tile[64][65];
    const float* ip = in + (size_t)blockIdx.z * slab;
    __hip_bfloat16* op = out + (size_t)blockIdx.z * slab;
    int r0 = blockIdx.x * 64, c0 = blockIdx.y * 64;
    int t = threadIdx.x;
    int tc = t & 63, tr = t >> 6;
    #pragma unroll
    for (int p = 0; p < 16; ++p) {
        int r = p * 4 + tr;
        tile[r][tc] = ip[(size_t)(r0 + r) * C + c0 + tc];
    }
    __syncthreads();
    #pragma unroll
    for (int p = 0; p < 16; ++p) {
        int c = p * 4 + tr;
        op[(size_t)(c0 + c) * R + r0 + tc] = tobf(tile[tc][c]);
    }
}

// ---------------- transpose + convert + PACK: weights -> fragment order ------
// in: slab R x C fp32 (R = k-dim, C = n-dim). out: packed chunks, nt base =
// blockIdx.z*ntPerSlab + c0/16. Each block: 64x64 tile -> 2 kt x 4 nt x 64 lanes.
__global__ __launch_bounds__(256) void tconv_pk(const float* __restrict__ in,
    unsigned short* __restrict__ out, int R, int C, int KT, size_t slab, int ntPerSlab)
{
    __shared__ float tile[64][65];
    const float* ip = in + (size_t)blockIdx.z * slab;
    int r0 = blockIdx.x * 64, c0 = blockIdx.y * 64;
    int t = threadIdx.x;
    int tc = t & 63, tr = t >> 6;
    #pragma unroll
    for (int p = 0; p < 16; ++p) {
        int r = p * 4 + tr;
        tile[r][tc] = ip[(size_t)(r0 + r) * C + c0 + tc];
    }
    __syncthreads();
    int ntb = blockIdx.z * ntPerSlab + (c0 >> 4);
    int ktb = r0 >> 5;
    #pragma unroll
    for (int p = 0; p < 2; ++p) {
        int cc = p * 256 + t;
        int lane = cc & 63, grp = cc >> 6;   // grp 0..7
        int ktl = grp & 1, ntl = grp >> 1;   // 2 kt x 4 nt
        int er = ktl * 32 + (lane >> 4) * 8;
        int dc = ntl * 16 + (lane & 15);
        u16x8 v;
        #pragma unroll
        for (int e = 0; e < 8; ++e) {
            __hip_bfloat16 h = tobf(tile[er + e][dc]);
            v[e] = *(unsigned short*)&h;
        }
        *(u16x8*)(out + pk(ntb + ntl, KT, ktb + ktl, lane)) = v;
    }
}

// ---------------- LayerNorm: fp32 in -> PACKED bf16 out (KT=24) -------------
__global__ __launch_bounds__(256) void ln_kernel(const float* __restrict__ in,
    const float* __restrict__ w, const float* __restrict__ b,
    __hip_bfloat16* __restrict__ out)
{
    int row = blockIdx.x;
    const float* x = in + (size_t)row * EQ;
    int t = threadIdx.x;
    float v0 = x[t];
    float v1 = x[t + 256];
    float v2 = x[t + 512];
    __shared__ float red[256];
    red[t] = v0 + v1 + v2;
    __syncthreads();
    for (int off = 128; off > 0; off >>= 1) {
        if (t < off) red[t] += red[t + off];
        __syncthreads();
    }
    float mu = red[0] * (1.0f / EQ);
    __syncthreads();
    float d0 = v0 - mu, d1 = v1 - mu, d2 = v2 - mu;
    red[t] = d0*d0 + d1*d1 + d2*d2;
    __syncthreads();
    for (int off = 128; off > 0; off >>= 1) {
        if (t < off) red[t] += red[t + off];
        __syncthreads();
    }
    float rs = rsqrtf(red[0] * (1.0f / EQ) + LN_EPS);
    int rt = row >> 4, rsl = row & 15;
    float n0 = d0 * rs * w[t]       + b[t];
    float n1 = d1 * rs * w[t + 256] + b[t + 256];
    float n2 = d2 * rs * w[t + 512] + b[t + 512];
    #pragma unroll
    for (int p = 0; p < 3; ++p) {
        int k = t + (p << 8);
        float val = p == 0 ? n0 : (p == 1 ? n1 : n2);
        int kt = k >> 5, lane = (((k >> 3) & 3) << 4) + rsl, e = k & 7;
        out[pk(rt, 24, kt, lane) + e] = tobf(val);
    }
}

// ---------------- packed-operand MFMA GEMM: no LDS staging, NO barriers -----
// A, B pre-packed in fragment order. Every fragment load = one coalesced 1KB
// wave transaction to VGPRs; depth-1 manual prefetch; waves stall independently
// so TLP (3 blocks/CU) hides L2 latency. Tile 128x128, 4 waves 2x2.
enum { EPI_NONE = 0, EPI_RES = 1, EPI_BIAS_GELU = 2, EPI_BIAS_RES = 3 };

template<int EPI, int KT>
__global__ __launch_bounds__(256) void mgemm_pk(
    const unsigned short* __restrict__ Apk, const unsigned short* __restrict__ Bpk,
    void* __restrict__ Cm, const float* __restrict__ bias,
    const float* __restrict__ res, int M, int N)
{
    const int tid = threadIdx.x;
    const int lane = tid & 63;
    const int w = tid >> 6;
    const int wr = w >> 1, wc = w & 1;
    const int l15 = lane & 15, quad = lane >> 4;
    const int row0 = blockIdx.x * 128, col0 = blockIdx.y * 128;
    const int rt0 = (row0 >> 4) + wr * 4;
    const int nt0 = (col0 >> 4) + wc * 4;

    f32x4 acc[4][4] = {};
    bf16x8 a[2][4], b[2][4];

    auto ld = [&](int buf, int kt) {
        #pragma unroll
        for (int i = 0; i < 4; ++i)
            a[buf][i] = *(const bf16x8*)(Apk + pk(rt0 + i, KT, kt, lane));
        #pragma unroll
        for (int j = 0; j < 4; ++j)
            b[buf][j] = *(const bf16x8*)(Bpk + pk(nt0 + j, KT, kt, lane));
    };

    ld(0, 0);
    #pragma unroll 2
    for (int kt = 0; kt < KT; ++kt) {
        int cur = kt & 1;
        if (kt + 1 < KT) ld(cur ^ 1, kt + 1);   // in flight across the MFMAs below
        #pragma unroll
        for (int i = 0; i < 4; ++i)
            #pragma unroll
            for (int j = 0; j < 4; ++j)
                acc[i][j] = __builtin_amdgcn_mfma_f32_16x16x32_bf16(a[cur][i], b[cur][j], acc[i][j], 0, 0, 0);
    }

    if constexpr (EPI == EPI_BIAS_GELU) {
        // C written PACKED (it is the next GEMM's A). C-frag -> LDS -> packed chunks.
        __shared__ unsigned short Cs[128][136];
        #pragma unroll
        for (int j = 0; j < 4; ++j) {
            float bv = bias[col0 + wc * 64 + j * 16 + l15];
            #pragma unroll
            for (int i = 0; i < 4; ++i)
                #pragma unroll
                for (int rg = 0; rg < 4; ++rg) {
                    float v = acc[i][j][rg] + bv;
                    v = 0.5f * v * (1.0f + erff(v * 0.70710678118654752f));
                    __hip_bfloat16 h = tobf(v);
                    Cs[wr * 64 + i * 16 + quad * 4 + rg][wc * 64 + j * 16 + l15] =
                        *(unsigned short*)&h;
                }
        }
        __syncthreads();
        const int KT2 = N >> 5;
        #pragma unroll
        for (int p = 0; p < 8; ++p) {
            int cc = p * 256 + tid;
            int ln2 = cc & 63, grp = cc >> 6;    // grp 0..31
            int ktl = grp & 3, rtl = grp >> 2;   // 4 kt x 8 rt
            int rowl = rtl * 16 + (ln2 & 15);
            u16x8 v;
            if (row0 + rowl < M) {
                #pragma unroll
                for (int e = 0; e < 8; ++e)
                    v[e] = Cs[rowl][ktl * 32 + (ln2 >> 4) * 8 + e];
            } else {
                #pragma unroll
                for (int e = 0; e < 8; ++e) v[e] = 0;
            }
            *(u16x8*)((unsigned short*)Cm + pk((row0 >> 4) + rtl, KT2, (col0 >> 5) + ktl, ln2)) = v;
        }
    } else {
        #pragma unroll
        for (int j = 0; j < 4; ++j) {
            int c = col0 + wc * 64 + j * 16 + l15;
            float bv = (EPI == EPI_BIAS_RES) ? bias[c] : 0.f;
            #pragma unroll
            for (int i = 0; i < 4; ++i)
                #pragma unroll
                for (int rg = 0; rg < 4; ++rg) {
                    int r = row0 + wr * 64 + i * 16 + quad * 4 + rg;
                    if (r < M) {
                        float v = acc[i][j][rg];
                        size_t idx = (size_t)r * N + c;
                        if (EPI == EPI_BIAS_RES) {
                            ((float*)Cm)[idx] = v + bv + res[idx];
                        } else {
                            ((__hip_bfloat16*)Cm)[idx] = tobf(v);
                        }
                    }
                }
        }
    }
}

// ---------------- staged MFMA GEMM (normal-layout A), kept for proj ---------
template<int EPI, bool OUTBF16, int TM>
__global__ __launch_bounds__(256) void mgemm(
    const unsigned short* __restrict__ A, const unsigned short* __restrict__ Bt,
    void* __restrict__ Cm, const float* __restrict__ bias,
    const float* __restrict__ res, int M, int N, int K)
{
    constexpr int AC = TM / 64;
    constexpr int IM = TM / 32;
    __shared__ __align__(16) unsigned short As[2][TM * 32];
    __shared__ __align__(16) unsigned short Bs[2][128 * 32];
    const int tid = threadIdx.x;
    const int lane = tid & 63;
    const int w = tid >> 6;
    const int wr = w >> 1, wc = w & 1;
    const int l15 = lane & 15, quad = lane >> 4;
    const int row0 = blockIdx.x * TM, col0 = blockIdx.y * 128;
    const int q = tid & 3;

    u16x8 ta[AC], tb[2];
    auto gload = [&](int k0) {
        #pragma unroll
        for (int c = 0; c < AC; ++c) {
            int row = (c * 256 + tid) >> 2;
            ta[c] = *(const u16x8*)(A + (size_t)(row0 + row) * K + k0 + q * 8);
        }
        #pragma unroll
        for (int c = 0; c < 2; ++c) {
            int row = (c * 256 + tid) >> 2;
            tb[c] = *(const u16x8*)(Bt + (size_t)(col0 + row) * K + k0 + q * 8);
        }
    };
    auto swrite = [&](int buf) {
        #pragma unroll
        for (int c = 0; c < AC; ++c) {
            int row = (c * 256 + tid) >> 2;
            int slot = (q + (row >> 1)) & 3;
            *(u16x8*)&As[buf][row * 32 + slot * 8] = ta[c];
        }
        #pragma unroll
        for (int c = 0; c < 2; ++c) {
            int row = (c * 256 + tid) >> 2;
            int slot = (q + (row >> 1)) & 3;
            *(u16x8*)&Bs[buf][row * 32 + slot * 8] = tb[c];
        }
    };

    f32x4 acc[IM][4] = {};
    const int nk = K >> 5;
    gload(0);
    swrite(0);
    __syncthreads();
    int cur = 0;
    for (int k = 0; k < nk; ++k) {
        if (k + 1 < nk) gload((k + 1) << 5);
        bf16x8 af[IM], bfr[4];
        #pragma unroll
        for (int i = 0; i < IM; ++i) {
            int r = wr * (IM * 16) + i * 16 + l15;
            int slot = (quad + (r >> 1)) & 3;
            af[i] = *(const bf16x8*)&As[cur][r * 32 + slot * 8];
        }
        #pragma unroll
        for (int j = 0; j < 4; ++j) {
            int r = wc * 64 + j * 16 + l15;
            int slot = (quad + (r >> 1)) & 3;
            bfr[j] = *(const bf16x8*)&Bs[cur][r * 32 + slot * 8];
        }
        #pragma unroll
        for (int i = 0; i < IM; ++i)
            #pragma unroll
            for (int j = 0; j < 4; ++j)
                acc[i][j] = __builtin_amdgcn_mfma_f32_16x16x32_bf16(af[i], bfr[j], acc[i][j], 0, 0, 0);
        if (k + 1 < nk) swrite(cur ^ 1);
        __syncthreads();
        cur ^= 1;
    }

    #pragma unroll
    for (int j = 0; j < 4; ++j) {
        int c = col0 + wc * 64 + j * 16 + l15;
        float bv = 0.f;
        if (EPI == EPI_BIAS_GELU || EPI == EPI_BIAS_RES) bv = bias[c];
        #pragma unroll
        for (int i = 0; i < IM; ++i) {
            #pragma unroll
            for (int rg = 0; rg < 4; ++rg) {
                int r = row0 + wr * (IM * 16) + i * 16 + quad * 4 + rg;
                if (r < M) {
                    float v = acc[i][j][rg];
                    size_t idx = (size_t)r * N + c;
                    if (EPI == EPI_RES) {
                        v += res[idx];
                    } else if (EPI == EPI_BIAS_GELU) {
                        v += bv;
                        v = 0.5f * v * (1.0f + erff(v * 0.70710678118654752f));
                    } else if (EPI == EPI_BIAS_RES) {
                        v += bv + res[idx];
                    }
                    if (OUTBF16) ((__hip_bfloat16*)Cm)[idx] = tobf(v);
                    else         ((float*)Cm)[idx] = v;
                }
            }
        }
    }
}

// ------------- fused scores+softmax: per (s-tile, bh) block -----------------
__global__ __launch_bounds__(256) void attn_sm(
    const unsigned short* __restrict__ qkv, unsigned short* __restrict__ att)
{
    const int s0 = blockIdx.x * 64;
    const int bh = blockIdx.y;
    const int b = bh / HQ, h = bh % HQ;
    const int tid = threadIdx.x;
    const int w = tid >> 6;
    const int lane = tid & 63;
    const int l15 = lane & 15, quad = lane >> 4;
    __shared__ float redm[4][64], reds[4][64];

    const size_t qbase = ((size_t)b * SQ) * QKV3 + h * DHQ;
    const size_t kbase = qbase + EQ;

    f32x4 acc[4][4] = {};
    #pragma unroll
    for (int ks = 0; ks < 2; ++ks) {
        bf16x8 af[4], bfr[4];
        #pragma unroll
        for (int i = 0; i < 4; ++i)
            af[i] = *(const bf16x8*)(qkv + qbase + (size_t)(s0 + i * 16 + l15) * QKV3 + ks * 32 + quad * 8);
        #pragma unroll
        for (int j = 0; j < 4; ++j)
            bfr[j] = *(const bf16x8*)(qkv + kbase + (size_t)(w * 64 + j * 16 + l15) * QKV3 + ks * 32 + quad * 8);
        #pragma unroll
        for (int i = 0; i < 4; ++i)
            #pragma unroll
            for (int j = 0; j < 4; ++j)
                acc[i][j] = __builtin_amdgcn_mfma_f32_16x16x32_bf16(af[i], bfr[j], acc[i][j], 0, 0, 0);
    }

    const float scale = 0.07124704998790965f;  // 1/sqrt(197)
    float sc[4][4][4];
    #pragma unroll
    for (int i = 0; i < 4; ++i)
        #pragma unroll
        for (int j = 0; j < 4; ++j) {
            bool ok = (w * 64 + j * 16 + l15) < SQ;
            #pragma unroll
            for (int rg = 0; rg < 4; ++rg)
                sc[i][rg][j] = ok ? acc[i][j][rg] * scale : -1e30f;
        }

    #pragma unroll
    for (int i = 0; i < 4; ++i)
        #pragma unroll
        for (int rg = 0; rg < 4; ++rg) {
            float m = fmaxf(fmaxf(sc[i][rg][0], sc[i][rg][1]), fmaxf(sc[i][rg][2], sc[i][rg][3]));
            #pragma unroll
            for (int d = 1; d < 16; d <<= 1) m = fmaxf(m, __shfl_xor(m, d));
            if (l15 == 0) redm[w][i * 16 + quad * 4 + rg] = m;
        }
    __syncthreads();

    float tot[4][4];
    #pragma unroll
    for (int i = 0; i < 4; ++i)
        #pragma unroll
        for (int rg = 0; rg < 4; ++rg) {
            int row = i * 16 + quad * 4 + rg;
            float m = fmaxf(fmaxf(redm[0][row], redm[1][row]),
                            fmaxf(redm[2][row], redm[3][row]));
            float s = 0.f;
            #pragma unroll
            for (int j = 0; j < 4; ++j) {
                float e = expf(sc[i][rg][j] - m);
                sc[i][rg][j] = e;
                s += e;
            }
            #pragma unroll
            for (int d = 1; d < 16; d <<= 1) s += __shfl_xor(s, d);
            if (l15 == 0) reds[w][row] = s;
            tot[i][rg] = 0.f;
        }
    __syncthreads();

    #pragma unroll
    for (int i = 0; i < 4; ++i)
        #pragma unroll
        for (int rg = 0; rg < 4; ++rg) {
            int row = i * 16 + quad * 4 + rg;
            tot[i][rg] = reds[0][row] + reds[1][row] + reds[2][row] + reds[3][row];
        }

    #pragma unroll
    for (int i = 0; i < 4; ++i)
        #pragma unroll
        for (int rg = 0; rg < 4; ++rg) {
            int srow = s0 + i * 16 + quad * 4 + rg;
            if (srow < SQ) {
                float inv = 1.0f / tot[i][rg];
                __hip_bfloat16* ap = (__hip_bfloat16*)att +
                    ((size_t)bh * SQ + srow) * TPAD + w * 64 + l15;
                #pragma unroll
                for (int j = 0; j < 4; ++j)
                    ap[j * 16] = tobf(sc[i][rg][j] * inv);
            }
        }
}

// ------------- o = att @ v : per (s-tile, bh) block, V^T staged in LDS ------
__global__ __launch_bounds__(256) void attv_mfma(
    const unsigned short* __restrict__ att, const unsigned short* __restrict__ qkv,
    __hip_bfloat16* __restrict__ o)
{
    __shared__ unsigned short Vs[64][264];
    const int s0 = blockIdx.x * 64;
    const int bh = blockIdx.y;
    const int b = bh / HQ, h = bh % HQ;
    const int tid = threadIdx.x;
    const int w = tid >> 6, lane = tid & 63;
    const int wr = w >> 1, wc = w & 1;
    const int l15 = lane & 15, quad = lane >> 4;

    const size_t vbase = ((size_t)b * SQ) * QKV3 + 2 * EQ + h * DHQ;
    {
        int t = tid;
        #pragma unroll
        for (int dch = 0; dch < 16; ++dch) {
            ushort4 u = *(const ushort4*)(qkv + vbase + (size_t)t * QKV3 + dch * 4);
            Vs[dch * 4 + 0][t] = u.x;
            Vs[dch * 4 + 1][t] = u.y;
            Vs[dch * 4 + 2][t] = u.z;
            Vs[dch * 4 + 3][t] = u.w;
        }
    }
    __syncthreads();

    const size_t arow = (size_t)bh * SQ + s0;
    f32x4 acc[2][2] = {};
    #pragma unroll
    for (int ks = 0; ks < 8; ++ks) {
        bf16x8 af[2], bfr[2];
        #pragma unroll
        for (int i = 0; i < 2; ++i)
            af[i] = *(const bf16x8*)(att + (arow + wr * 32 + i * 16 + l15) * TPAD + ks * 32 + quad * 8);
        #pragma unroll
        for (int j = 0; j < 2; ++j)
            bfr[j] = *(const bf16x8*)&Vs[wc * 32 + j * 16 + l15][ks * 32 + quad * 8];
        #pragma unroll
        for (int i = 0; i < 2; ++i)
            #pragma unroll
            for (int j = 0; j < 2; ++j)
                acc[i][j] = __builtin_amdgcn_mfma_f32_16x16x32_bf16(af[i], bfr[j], acc[i][j], 0, 0, 0);
    }

    #pragma unroll
    for (int i = 0; i < 2; ++i)
        #pragma unroll
        for (int rg = 0; rg < 4; ++rg) {
            int srow = s0 + wr * 32 + i * 16 + quad * 4 + rg;
            if (srow < SQ) {
                __hip_bfloat16* op = o + ((size_t)b * SQ + srow) * EQ + h * DHQ + wc * 32 + l15;
                #pragma unroll
                for (int j = 0; j < 2; ++j)
                    op[j * 16] = tobf(acc[i][j][rg]);
            }
        }
}

// ---------------- classifier: logits GEMV (parallel) + softmax --------------
__global__ __launch_bounds__(256) void logits_kernel(
    const float* __restrict__ hbuf, const float* __restrict__ Wc,
    const float* __restrict__ bc, float* __restrict__ logits)
{
    __shared__ __align__(16) float hs[768];
    int b = blockIdx.y;
    int c = blockIdx.x * 256 + threadIdx.x;
    const float* hr = hbuf + (size_t)b * SQ * EQ;
    for (int p = threadIdx.x; p < 192; p += 256)
        *(float4*)&hs[p << 2] = *(const float4*)(hr + (p << 2));
    __syncthreads();
    if (c < CQ) {
        float s = bc[c];
        #pragma unroll 8
        for (int e = 0; e < EQ; ++e)
            s = fmaf(hs[e], Wc[(size_t)e * CQ + c], s);
        logits[(size_t)b * CQ + c] = s;
    }
}

__global__ __launch_bounds__(256) void smax_kernel(
    const float* __restrict__ logits, float* __restrict__ out)
{
    __shared__ float red[256];
    int b = blockIdx.x;
    int t = threadIdx.x;
    const float* lp = logits + (size_t)b * CQ;
    float lg[4];
    #pragma unroll
    for (int j = 0; j < 4; ++j) {
        int c = t + j * 256;
        lg[j] = (c < CQ) ? lp[c] : -1e30f;
    }
    float m = fmaxf(fmaxf(lg[0], lg[1]), fmaxf(lg[2], lg[3]));
    red[t] = m;
    __syncthreads();
    for (int off = 128; off; off >>= 1) {
        if (t < off) red[t] = fmaxf(red[t], red[t + off]);
        __syncthreads();
    }
    m = red[0];
    __syncthreads();
    float ex[4], s = 0.f;
    #pragma unroll
    for (int j = 0; j < 4; ++j) {
        ex[j] = (t + j * 256 < CQ) ? expf(lg[j] - m) : 0.f;
        s += ex[j];
    }
    red[t] = s;
    __syncthreads();
    for (int off = 128; off; off >>= 1) {
        if (t < off) red[t] += red[t + off];
        __syncthreads();
    }
    float inv = 1.0f / red[0];
    #pragma unroll
    for (int j = 0; j < 4; ++j)
        if (t + j * 256 < CQ) out[(size_t)b * CQ + t + j * 256] = ex[j] * inv;
}

extern "C" void kernel_launch(void* const* d_in, const int* in_sizes, int n_in,
                              void* d_out, int out_size, void* d_ws, size_t ws_size,
                              hipStream_t stream)
{
    const float* x     = (const float*)d_in[0];
    const float* Wk    = (const float*)d_in[1];
    const float* Wq    = (const float*)d_in[2];
    const float* Wv    = (const float*)d_in[3];
    const float* Wconv = (const float*)d_in[4];
    const float* ln1w  = (const float*)d_in[5];
    const float* ln1b  = (const float*)d_in[6];
    const float* ln2w  = (const float*)d_in[7];
    const float* ln2b  = (const float*)d_in[8];
    const float* W1    = (const float*)d_in[9];
    const float* b1    = (const float*)d_in[10];
    const float* W2    = (const float*)d_in[11];
    const float* b2    = (const float*)d_in[12];
    const float* Wc    = (const float*)d_in[13];
    const float* bc    = (const float*)d_in[14];
    float* out = (float*)d_out;

    const size_t BSE   = (size_t)BSQ * EQ;
    const size_t ATTR  = (size_t)BQ * HQ * SQ + 64;

    float* w = (float*)d_ws;
    float* bh    = w; w += BSE;
    float* res1  = w; w += BSE;
    float* logit = w; w += (size_t)BQ * CQ;
    __hip_bfloat16* qkvbf = (__hip_bfloat16*)w; w += (size_t)MPAD * QKV3 / 2;
    __hip_bfloat16* actb  = (__hip_bfloat16*)w; w += (size_t)MPAD * EQ / 2;   // packed ln out / normal o
    __hip_bfloat16* attbf = (__hip_bfloat16*)w; w += ATTR * TPAD / 2;
    __hip_bfloat16* wbuf  = (__hip_bfloat16*)w;
    __hip_bfloat16* ffh   = attbf;                                            // packed ffh overlays attbf

    const size_t WQKV = (size_t)EQ * EQ;   // 48 nt x 24 kt x 512 = 589824 (packed slab size matches)
    __hip_bfloat16* WqT = wbuf;            // packed nt 0..47
    __hip_bfloat16* WkT = wbuf + WQKV;     // packed nt 48..95
    __hip_bfloat16* WvT = wbuf + 2 * WQKV; // packed nt 96..143
    __hip_bfloat16* WcvT = wbuf;           // phase B: normal [n][k] for proj
    __hip_bfloat16* W1T  = wbuf + WQKV;    // packed
    __hip_bfloat16* W2T  = W1T + (size_t)EQ * FQ;  // packed

    for (int l = 0; l < LQ; ++l) {
        const float* hin = (l == 0) ? x : bh;
        tconv_pk<<<dim3(12, 1, HQ), 256, 0, stream>>>(Wq + (size_t)l * HQ * EQ * DHQ, (unsigned short*)WqT, EQ, DHQ, 24, (size_t)EQ * DHQ, 4);
        tconv_pk<<<dim3(12, 1, HQ), 256, 0, stream>>>(Wk + (size_t)l * HQ * EQ * DHQ, (unsigned short*)WkT, EQ, DHQ, 24, (size_t)EQ * DHQ, 4);
        tconv_pk<<<dim3(12, 1, HQ), 256, 0, stream>>>(Wv + (size_t)l * HQ * EQ * DHQ, (unsigned short*)WvT, EQ, DHQ, 24, (size_t)EQ * DHQ, 4);

        ln_kernel<<<BSQ, 256, 0, stream>>>(hin, ln1w + l * EQ, ln1b + l * EQ, actb);

        mgemm_pk<EPI_NONE, 24><<<dim3(50, 18), 256, 0, stream>>>(
            (const unsigned short*)actb, (const unsigned short*)wbuf, qkvbf, nullptr, nullptr, BSQ, QKV3);

        tconv<<<dim3(12, 12, 1), 256, 0, stream>>>(Wconv + (size_t)l * EQ * EQ, WcvT, EQ, EQ, 0);
        tconv_pk<<<dim3(12, 32, 1), 256, 0, stream>>>(W1 + (size_t)l * EQ * FQ, (unsigned short*)W1T, EQ, FQ, 24, 0, 0);
        tconv_pk<<<dim3(32, 12, 1), 256, 0, stream>>>(W2 + (size_t)l * FQ * EQ, (unsigned short*)W2T, FQ, EQ, 64, 0, 0);

        attn_sm<<<dim3(4, BQ * HQ), 256, 0, stream>>>((const unsigned short*)qkvbf, (unsigned short*)attbf);
        attv_mfma<<<dim3(4, BQ * HQ), 256, 0, stream>>>((const unsigned short*)attbf, (const unsigned short*)qkvbf, actb);

        mgemm<EPI_RES, false, 64><<<dim3(100, 6), 256, 0, stream>>>(
            (const unsigned short*)actb, (const unsigned short*)WcvT, res1, nullptr, hin, BSQ, EQ, EQ);

        ln_kernel<<<BSQ, 256, 0, stream>>>(res1, ln2w + l * EQ, ln2b + l * EQ, actb);

        mgemm_pk<EPI_BIAS_GELU, 24><<<dim3(50, 16), 256, 0, stream>>>(
            (const unsigned short*)actb, (const unsigned short*)W1T, ffh, b1 + l * FQ, nullptr, BSQ, FQ);
        mgemm_pk<EPI_BIAS_RES, 64><<<dim3(50, 6), 256, 0, stream>>>(
            (const unsigned short*)ffh, (const unsigned short*)W2T, bh, b2 + l * EQ, res1, BSQ, EQ);
    }
    logits_kernel<<<dim3(4, BQ), 256, 0, stream>>>(bh, Wc, bc, logit);
    smax_kernel<<<BQ, 256, 0, stream>>>(logit, out);
}

// Round 8
// 1223.337 us; speedup vs baseline: 1.7934x; 1.0486x over previous
//
#include <hip/hip_runtime.h>
#include <hip/hip_bf16.h>
#include <math.h>

#define BQ 32
#define SQ 197
#define EQ 768
#define HQ 12
#define DHQ 64
#define FQ 2048
#define LQ 4
#define CQ 1000
#define BSQ (BQ*SQ)     // 6304
#define SP 208          // padded rows per batch (13 * 16)
#define MP (BQ*SP)      // 6656 padded total rows (52 tiles of 128)
#define MP2 (MP+64)     // qkvbf row allocation (attv/attn read up to b*208+255)
#define NRT 52          // 128-row tiles
#define QKV3 2304       // fused q|k|v row width
#define TPAD 256        // attention t-dim padded
#define LN_EPS 1e-5f

typedef __bf16 bf16x8 __attribute__((ext_vector_type(8)));
typedef float f32x4 __attribute__((ext_vector_type(4)));
typedef unsigned short u16x8 __attribute__((ext_vector_type(8)));

__device__ __forceinline__ __hip_bfloat16 tobf(float f) { return __float2bfloat16(f); }

// Packed fragment layout: chunk of 8 bf16 for (row-tile rt, k-tile kt, lane):
//   buf[pk(rt,KT,kt,lane)+e] <-> A[rt*16+(lane&15)][kt*32+(lane>>4)*8+e]
// A wave's 64 lanes' chunks are consecutive -> one coalesced 1KB load/fragment.
__device__ __forceinline__ size_t pk(int rt, int KT, int kt, int lane) {
    return (((size_t)rt * KT + kt) * 64 + (size_t)lane) * 8;
}

// ---------------- copy x into padded residual stream ------------------------
__global__ __launch_bounds__(256) void copy_pad(const float* __restrict__ x,
    float* __restrict__ bh)
{
    int r = blockIdx.x;                 // 0..6303
    int b = r / SQ, s = r % SQ;
    const float* src = x + (size_t)r * EQ;
    float* dst = bh + ((size_t)b * SP + s) * EQ;
    int t = threadIdx.x;
    dst[t] = src[t];
    dst[t + 256] = src[t + 256];
    dst[t + 512] = src[t + 512];
}

// ---------------- transpose + convert + PACK: weights -> fragment order -----
// in: slab R x C fp32 (R = k-dim, C = n-dim). nt base = z*ntPerSlab + c0/16.
__global__ __launch_bounds__(256) void tconv_pk(const float* __restrict__ in,
    unsigned short* __restrict__ out, int R, int C, int KT, size_t slab, int ntPerSlab)
{
    __shared__ float tile[64][65];
    const float* ip = in + (size_t)blockIdx.z * slab;
    int r0 = blockIdx.x * 64, c0 = blockIdx.y * 64;
    int t = threadIdx.x;
    int tc = t & 63, tr = t >> 6;
    #pragma unroll
    for (int p = 0; p < 16; ++p) {
        int r = p * 4 + tr;
        tile[r][tc] = ip[(size_t)(r0 + r) * C + c0 + tc];
    }
    __syncthreads();
    int ntb = blockIdx.z * ntPerSlab + (c0 >> 4);
    int ktb = r0 >> 5;
    #pragma unroll
    for (int p = 0; p < 2; ++p) {
        int cc = p * 256 + t;
        int lane = cc & 63, grp = cc >> 6;   // 2 kt x 4 nt
        int ktl = grp & 1, ntl = grp >> 1;
        int er = ktl * 32 + (lane >> 4) * 8;
        int dc = ntl * 16 + (lane & 15);
        u16x8 v;
        #pragma unroll
        for (int e = 0; e < 8; ++e) {
            __hip_bfloat16 h = tobf(tile[er + e][dc]);
            v[e] = *(unsigned short*)&h;
        }
        *(u16x8*)(out + pk(ntb + ntl, KT, ktb + ktl, lane)) = v;
    }
}

// ---------------- LayerNorm: fp32 (padded rows) -> PACKED bf16 (KT=24) ------
__global__ __launch_bounds__(256) void ln_kernel(const float* __restrict__ in,
    const float* __restrict__ w, const float* __restrict__ b,
    __hip_bfloat16* __restrict__ out)
{
    int row = blockIdx.x;
    const float* x = in + (size_t)row * EQ;
    int t = threadIdx.x;
    float v0 = x[t];
    float v1 = x[t + 256];
    float v2 = x[t + 512];
    __shared__ float red[256];
    red[t] = v0 + v1 + v2;
    __syncthreads();
    for (int off = 128; off > 0; off >>= 1) {
        if (t < off) red[t] += red[t + off];
        __syncthreads();
    }
    float mu = red[0] * (1.0f / EQ);
    __syncthreads();
    float d0 = v0 - mu, d1 = v1 - mu, d2 = v2 - mu;
    red[t] = d0*d0 + d1*d1 + d2*d2;
    __syncthreads();
    for (int off = 128; off > 0; off >>= 1) {
        if (t < off) red[t] += red[t + off];
        __syncthreads();
    }
    float rs = rsqrtf(red[0] * (1.0f / EQ) + LN_EPS);
    int rt = row >> 4, rsl = row & 15;
    float n0 = d0 * rs * w[t]       + b[t];
    float n1 = d1 * rs * w[t + 256] + b[t + 256];
    float n2 = d2 * rs * w[t + 512] + b[t + 512];
    #pragma unroll
    for (int p = 0; p < 3; ++p) {
        int k = t + (p << 8);
        float val = p == 0 ? n0 : (p == 1 ? n1 : n2);
        int kt = k >> 5, lane = (((k >> 3) & 3) << 4) + rsl, e = k & 7;
        out[pk(rt, 24, kt, lane) + e] = tobf(val);
    }
}

// ---------------- packed-operand MFMA GEMM: no LDS staging, no barriers -----
// XCD row-group swizzle: 1D grid, g=bid&7 -> XCD; each g owns a contiguous
// band of 128-row tiles, columns sweep fastest -> per-XCD L2 holds one hot
// A-row-tile + all of B. Depth-1 register prefetch; waves stall independently.
enum { EPI_NONE = 0, EPI_RES = 1, EPI_BIAS_GELU = 2, EPI_BIAS_RES = 3 };

template<int EPI, int KT>
__global__ __launch_bounds__(256) void mgemm_pk(
    const unsigned short* __restrict__ Apk, const unsigned short* __restrict__ Bpk,
    void* __restrict__ Cm, const float* __restrict__ bias,
    const float* __restrict__ res, int N, int nNT)
{
    const int g = blockIdx.x & 7;
    const int sIdx = blockIdx.x >> 3;
    const int b0 = (NRT * g) >> 3, b1 = (NRT * (g + 1)) >> 3;
    const int colT = sIdx % nNT, rloc = sIdx / nNT;
    if (b0 + rloc >= b1) return;
    const int row0 = (b0 + rloc) << 7, col0 = colT << 7;

    const int tid = threadIdx.x;
    const int lane = tid & 63;
    const int w = tid >> 6;
    const int wr = w >> 1, wc = w & 1;
    const int l15 = lane & 15, quad = lane >> 4;
    const int rt0 = (row0 >> 4) + wr * 4;
    const int nt0 = (col0 >> 4) + wc * 4;

    f32x4 acc[4][4] = {};
    bf16x8 a[2][4], b[2][4];

    auto ld = [&](int buf, int kt) {
        #pragma unroll
        for (int i = 0; i < 4; ++i)
            a[buf][i] = *(const bf16x8*)(Apk + pk(rt0 + i, KT, kt, lane));
        #pragma unroll
        for (int j = 0; j < 4; ++j)
            b[buf][j] = *(const bf16x8*)(Bpk + pk(nt0 + j, KT, kt, lane));
    };

    ld(0, 0);
    #pragma unroll 2
    for (int kt = 0; kt < KT; ++kt) {
        int cur = kt & 1;
        if (kt + 1 < KT) ld(cur ^ 1, kt + 1);
        #pragma unroll
        for (int i = 0; i < 4; ++i)
            #pragma unroll
            for (int j = 0; j < 4; ++j)
                acc[i][j] = __builtin_amdgcn_mfma_f32_16x16x32_bf16(a[cur][i], b[cur][j], acc[i][j], 0, 0, 0);
    }

    if constexpr (EPI == EPI_BIAS_GELU) {
        // C written PACKED (next GEMM's A): frag -> LDS -> packed chunks.
        __shared__ unsigned short Cs[128][136];
        #pragma unroll
        for (int j = 0; j < 4; ++j) {
            float bv = bias[col0 + wc * 64 + j * 16 + l15];
            #pragma unroll
            for (int i = 0; i < 4; ++i)
                #pragma unroll
                for (int rg = 0; rg < 4; ++rg) {
                    float v = acc[i][j][rg] + bv;
                    v = 0.5f * v * (1.0f + erff(v * 0.70710678118654752f));
                    __hip_bfloat16 h = tobf(v);
                    Cs[wr * 64 + i * 16 + quad * 4 + rg][wc * 64 + j * 16 + l15] =
                        *(unsigned short*)&h;
                }
        }
        __syncthreads();
        const int KT2 = N >> 5;
        #pragma unroll
        for (int p = 0; p < 8; ++p) {
            int cc = p * 256 + tid;
            int ln2 = cc & 63, grp = cc >> 6;    // 4 kt x 8 rt
            int ktl = grp & 3, rtl = grp >> 2;
            int rowl = rtl * 16 + (ln2 & 15);
            u16x8 v;
            #pragma unroll
            for (int e = 0; e < 8; ++e)
                v[e] = Cs[rowl][ktl * 32 + (ln2 >> 4) * 8 + e];
            *(u16x8*)((unsigned short*)Cm + pk((row0 >> 4) + rtl, KT2, (col0 >> 5) + ktl, ln2)) = v;
        }
    } else {
        #pragma unroll
        for (int j = 0; j < 4; ++j) {
            int c = col0 + wc * 64 + j * 16 + l15;
            float bv = (EPI == EPI_BIAS_RES) ? bias[c] : 0.f;
            #pragma unroll
            for (int i = 0; i < 4; ++i)
                #pragma unroll
                for (int rg = 0; rg < 4; ++rg) {
                    int r = row0 + wr * 64 + i * 16 + quad * 4 + rg;
                    float v = acc[i][j][rg];
                    size_t idx = (size_t)r * N + c;
                    if (EPI == EPI_BIAS_RES) {
                        ((float*)Cm)[idx] = v + bv + res[idx];
                    } else if (EPI == EPI_RES) {
                        ((float*)Cm)[idx] = v + res[idx];
                    } else {
                        ((__hip_bfloat16*)Cm)[idx] = tobf(v);
                    }
                }
        }
    }
}

// ------------- fused scores+softmax: per (s-tile, bh) block -----------------
__global__ __launch_bounds__(256) void attn_sm(
    const unsigned short* __restrict__ qkv, unsigned short* __restrict__ att)
{
    const int s0 = blockIdx.x * 64;
    const int bh = blockIdx.y;
    const int b = bh / HQ, h = bh % HQ;
    const int tid = threadIdx.x;
    const int w = tid >> 6;
    const int lane = tid & 63;
    const int l15 = lane & 15, quad = lane >> 4;
    __shared__ float redm[4][64], reds[4][64];

    const size_t qbase = ((size_t)b * SP) * QKV3 + h * DHQ;
    const size_t kbase = qbase + EQ;

    f32x4 acc[4][4] = {};
    #pragma unroll
    for (int ks = 0; ks < 2; ++ks) {
        bf16x8 af[4], bfr[4];
        #pragma unroll
        for (int i = 0; i < 4; ++i)
            af[i] = *(const bf16x8*)(qkv + qbase + (size_t)(s0 + i * 16 + l15) * QKV3 + ks * 32 + quad * 8);
        #pragma unroll
        for (int j = 0; j < 4; ++j)
            bfr[j] = *(const bf16x8*)(qkv + kbase + (size_t)(w * 64 + j * 16 + l15) * QKV3 + ks * 32 + quad * 8);
        #pragma unroll
        for (int i = 0; i < 4; ++i)
            #pragma unroll
            for (int j = 0; j < 4; ++j)
                acc[i][j] = __builtin_amdgcn_mfma_f32_16x16x32_bf16(af[i], bfr[j], acc[i][j], 0, 0, 0);
    }

    const float scale = 0.07124704998790965f;  // 1/sqrt(197)
    float sc[4][4][4];
    #pragma unroll
    for (int i = 0; i < 4; ++i)
        #pragma unroll
        for (int j = 0; j < 4; ++j) {
            bool ok = (w * 64 + j * 16 + l15) < SQ;
            #pragma unroll
            for (int rg = 0; rg < 4; ++rg)
                sc[i][rg][j] = ok ? acc[i][j][rg] * scale : -1e30f;
        }

    #pragma unroll
    for (int i = 0; i < 4; ++i)
        #pragma unroll
        for (int rg = 0; rg < 4; ++rg) {
            float m = fmaxf(fmaxf(sc[i][rg][0], sc[i][rg][1]), fmaxf(sc[i][rg][2], sc[i][rg][3]));
            #pragma unroll
            for (int d = 1; d < 16; d <<= 1) m = fmaxf(m, __shfl_xor(m, d));
            if (l15 == 0) redm[w][i * 16 + quad * 4 + rg] = m;
        }
    __syncthreads();

    float tot[4][4];
    #pragma unroll
    for (int i = 0; i < 4; ++i)
        #pragma unroll
        for (int rg = 0; rg < 4; ++rg) {
            int row = i * 16 + quad * 4 + rg;
            float m = fmaxf(fmaxf(redm[0][row], redm[1][row]),
                            fmaxf(redm[2][row], redm[3][row]));
            float s = 0.f;
            #pragma unroll
            for (int j = 0; j < 4; ++j) {
                float e = expf(sc[i][rg][j] - m);
                sc[i][rg][j] = e;
                s += e;
            }
            #pragma unroll
            for (int d = 1; d < 16; d <<= 1) s += __shfl_xor(s, d);
            if (l15 == 0) reds[w][row] = s;
            tot[i][rg] = 0.f;
        }
    __syncthreads();

    #pragma unroll
    for (int i = 0; i < 4; ++i)
        #pragma unroll
        for (int rg = 0; rg < 4; ++rg) {
            int row = i * 16 + quad * 4 + rg;
            tot[i][rg] = reds[0][row] + reds[1][row] + reds[2][row] + reds[3][row];
        }

    #pragma unroll
    for (int i = 0; i < 4; ++i)
        #pragma unroll
        for (int rg = 0; rg < 4; ++rg) {
            int srow = s0 + i * 16 + quad * 4 + rg;
            if (srow < SQ) {
                float inv = 1.0f / tot[i][rg];
                __hip_bfloat16* ap = (__hip_bfloat16*)att +
                    ((size_t)bh * SQ + srow) * TPAD + w * 64 + l15;
                #pragma unroll
                for (int j = 0; j < 4; ++j)
                    ap[j * 16] = tobf(sc[i][rg][j] * inv);
            }
        }
}

// ------------- o = att @ v : V^T in LDS, output PACKED (proj's A) -----------
__global__ __launch_bounds__(256) void attv_mfma(
    const unsigned short* __restrict__ att, const unsigned short* __restrict__ qkv,
    unsigned short* __restrict__ opk)
{
    __shared__ unsigned short Vs[64][264];
    __shared__ unsigned short Cs[64][72];
    const int s0 = blockIdx.x * 64;
    const int bh = blockIdx.y;
    const int b = bh / HQ, h = bh % HQ;
    const int tid = threadIdx.x;
    const int w = tid >> 6, lane = tid & 63;
    const int wr = w >> 1, wc = w & 1;
    const int l15 = lane & 15, quad = lane >> 4;

    const size_t vbase = ((size_t)b * SP) * QKV3 + 2 * EQ + h * DHQ;
    {
        int t = tid;
        #pragma unroll
        for (int dch = 0; dch < 16; ++dch) {
            ushort4 u = *(const ushort4*)(qkv + vbase + (size_t)t * QKV3 + dch * 4);
            Vs[dch * 4 + 0][t] = u.x;
            Vs[dch * 4 + 1][t] = u.y;
            Vs[dch * 4 + 2][t] = u.z;
            Vs[dch * 4 + 3][t] = u.w;
        }
    }
    __syncthreads();

    const size_t arow = (size_t)bh * SQ + s0;
    f32x4 acc[2][2] = {};
    #pragma unroll
    for (int ks = 0; ks < 8; ++ks) {
        bf16x8 af[2], bfr[2];
        #pragma unroll
        for (int i = 0; i < 2; ++i)
            af[i] = *(const bf16x8*)(att + (arow + wr * 32 + i * 16 + l15) * TPAD + ks * 32 + quad * 8);
        #pragma unroll
        for (int j = 0; j < 2; ++j)
            bfr[j] = *(const bf16x8*)&Vs[wc * 32 + j * 16 + l15][ks * 32 + quad * 8];
        #pragma unroll
        for (int i = 0; i < 2; ++i)
            #pragma unroll
            for (int j = 0; j < 2; ++j)
                acc[i][j] = __builtin_amdgcn_mfma_f32_16x16x32_bf16(af[i], bfr[j], acc[i][j], 0, 0, 0);
    }

    // frag -> LDS tile -> packed chunks (rows beyond this batch masked out)
    #pragma unroll
    for (int i = 0; i < 2; ++i)
        #pragma unroll
        for (int j = 0; j < 2; ++j)
            #pragma unroll
            for (int rg = 0; rg < 4; ++rg) {
                __hip_bfloat16 hv = tobf(acc[i][j][rg]);
                Cs[wr * 32 + i * 16 + quad * 4 + rg][wc * 32 + j * 16 + l15] =
                    *(unsigned short*)&hv;
            }
    __syncthreads();

    const int rt0 = ((b * SP) >> 4) + (s0 >> 4);
    const int kt0 = h * 2;
    int validRt = (SP - s0) >> 4; if (validRt > 4) validRt = 4;
    #pragma unroll
    for (int p = 0; p < 2; ++p) {
        int cc = p * 256 + tid;
        int ln2 = cc & 63, grp = cc >> 6;    // 2 kt x 4 rt
        int ktl = grp & 1, rtl = grp >> 1;
        if (rtl < validRt) {
            int rowl = rtl * 16 + (ln2 & 15);
            int colb = ktl * 32 + (ln2 >> 4) * 8;
            u16x8 v;
            #pragma unroll
            for (int e = 0; e < 8; ++e)
                v[e] = Cs[rowl][colb + e];
            *(u16x8*)(opk + pk(rt0 + rtl, 24, kt0 + ktl, ln2)) = v;
        }
    }
}

// ---------------- classifier: logits GEMV (parallel) + softmax --------------
__global__ __launch_bounds__(256) void logits_kernel(
    const float* __restrict__ hbuf, const float* __restrict__ Wc,
    const float* __restrict__ bc, float* __restrict__ logits)
{
    __shared__ __align__(16) float hs[768];
    int b = blockIdx.y;
    int c = blockIdx.x * 256 + threadIdx.x;
    const float* hr = hbuf + (size_t)b * SP * EQ;   // s=0 row
    for (int p = threadIdx.x; p < 192; p += 256)
        *(float4*)&hs[p << 2] = *(const float4*)(hr + (p << 2));
    __syncthreads();
    if (c < CQ) {
        float s = bc[c];
        #pragma unroll 8
        for (int e = 0; e < EQ; ++e)
            s = fmaf(hs[e], Wc[(size_t)e * CQ + c], s);
        logits[(size_t)b * CQ + c] = s;
    }
}

__global__ __launch_bounds__(256) void smax_kernel(
    const float* __restrict__ logits, float* __restrict__ out)
{
    __shared__ float red[256];
    int b = blockIdx.x;
    int t = threadIdx.x;
    const float* lp = logits + (size_t)b * CQ;
    float lg[4];
    #pragma unroll
    for (int j = 0; j < 4; ++j) {
        int c = t + j * 256;
        lg[j] = (c < CQ) ? lp[c] : -1e30f;
    }
    float m = fmaxf(fmaxf(lg[0], lg[1]), fmaxf(lg[2], lg[3]));
    red[t] = m;
    __syncthreads();
    for (int off = 128; off; off >>= 1) {
        if (t < off) red[t] = fmaxf(red[t], red[t + off]);
        __syncthreads();
    }
    m = red[0];
    __syncthreads();
    float ex[4], s = 0.f;
    #pragma unroll
    for (int j = 0; j < 4; ++j) {
        ex[j] = (t + j * 256 < CQ) ? expf(lg[j] - m) : 0.f;
        s += ex[j];
    }
    red[t] = s;
    __syncthreads();
    for (int off = 128; off; off >>= 1) {
        if (t < off) red[t] += red[t + off];
        __syncthreads();
    }
    float inv = 1.0f / red[0];
    #pragma unroll
    for (int j = 0; j < 4; ++j)
        if (t + j * 256 < CQ) out[(size_t)b * CQ + t + j * 256] = ex[j] * inv;
}

extern "C" void kernel_launch(void* const* d_in, const int* in_sizes, int n_in,
                              void* d_out, int out_size, void* d_ws, size_t ws_size,
                              hipStream_t stream)
{
    const float* x     = (const float*)d_in[0];
    const float* Wk    = (const float*)d_in[1];
    const float* Wq    = (const float*)d_in[2];
    const float* Wv    = (const float*)d_in[3];
    const float* Wconv = (const float*)d_in[4];
    const float* ln1w  = (const float*)d_in[5];
    const float* ln1b  = (const float*)d_in[6];
    const float* ln2w  = (const float*)d_in[7];
    const float* ln2b  = (const float*)d_in[8];
    const float* W1    = (const float*)d_in[9];
    const float* b1    = (const float*)d_in[10];
    const float* W2    = (const float*)d_in[11];
    const float* b2    = (const float*)d_in[12];
    const float* Wc    = (const float*)d_in[13];
    const float* bc    = (const float*)d_in[14];
    float* out = (float*)d_out;

    const size_t MPE   = (size_t)MP * EQ;             // padded rows x E
    const size_t ATTR  = (size_t)BQ * HQ * SQ + 64;

    float* w = (float*)d_ws;
    float* bh    = w; w += MPE;                        // padded residual stream
    float* res1  = w; w += MPE;                        // padded post-attn residual
    float* logit = w; w += (size_t)BQ * CQ;
    __hip_bfloat16* qkvbf = (__hip_bfloat16*)w; w += (size_t)MP2 * QKV3 / 2;
    __hip_bfloat16* actb  = (__hip_bfloat16*)w; w += MPE / 2;     // packed activations
    __hip_bfloat16* attbf = (__hip_bfloat16*)w; w += ATTR * TPAD / 2;
    __hip_bfloat16* wbuf  = (__hip_bfloat16*)w;
    __hip_bfloat16* ffh   = attbf;                    // packed ffh overlays attbf

    const size_t WQKV = (size_t)EQ * EQ;
    __hip_bfloat16* WqT = wbuf;                       // packed nt 0..47
    __hip_bfloat16* WkT = wbuf + WQKV;                // packed nt 48..95
    __hip_bfloat16* WvT = wbuf + 2 * WQKV;            // packed nt 96..143
    __hip_bfloat16* WcvT = wbuf;                      // phase B overlays (packed)
    __hip_bfloat16* W1T  = wbuf + WQKV;               // packed
    __hip_bfloat16* W2T  = W1T + (size_t)EQ * FQ;     // packed (KT=64)

    copy_pad<<<BSQ, 256, 0, stream>>>(x, bh);

    for (int l = 0; l < LQ; ++l) {
        tconv_pk<<<dim3(12, 1, HQ), 256, 0, stream>>>(Wq + (size_t)l * HQ * EQ * DHQ, (unsigned short*)WqT, EQ, DHQ, 24, (size_t)EQ * DHQ, 4);
        tconv_pk<<<dim3(12, 1, HQ), 256, 0, stream>>>(Wk + (size_t)l * HQ * EQ * DHQ, (unsigned short*)WkT, EQ, DHQ, 24, (size_t)EQ * DHQ, 4);
        tconv_pk<<<dim3(12, 1, HQ), 256, 0, stream>>>(Wv + (size_t)l * HQ * EQ * DHQ, (unsigned short*)WvT, EQ, DHQ, 24, (size_t)EQ * DHQ, 4);

        ln_kernel<<<MP, 256, 0, stream>>>(bh, ln1w + l * EQ, ln1b + l * EQ, actb);

        // QKV: N=2304, 18 col-tiles, XCD-swizzled grid 8*7*18
        mgemm_pk<EPI_NONE, 24><<<8 * 7 * 18, 256, 0, stream>>>(
            (const unsigned short*)actb, (const unsigned short*)wbuf, qkvbf, nullptr, nullptr, QKV3, 18);

        tconv_pk<<<dim3(12, 12, 1), 256, 0, stream>>>(Wconv + (size_t)l * EQ * EQ, (unsigned short*)WcvT, EQ, EQ, 24, 0, 0);
        tconv_pk<<<dim3(12, 32, 1), 256, 0, stream>>>(W1 + (size_t)l * EQ * FQ, (unsigned short*)W1T, EQ, FQ, 24, 0, 0);
        tconv_pk<<<dim3(32, 12, 1), 256, 0, stream>>>(W2 + (size_t)l * FQ * EQ, (unsigned short*)W2T, FQ, EQ, 64, 0, 0);

        attn_sm<<<dim3(4, BQ * HQ), 256, 0, stream>>>((const unsigned short*)qkvbf, (unsigned short*)attbf);
        attv_mfma<<<dim3(4, BQ * HQ), 256, 0, stream>>>((const unsigned short*)attbf, (const unsigned short*)qkvbf, (unsigned short*)actb);

        // proj: packed A (attv out), packed Wconv; C=res1 fp32 + residual bh
        mgemm_pk<EPI_RES, 24><<<8 * 7 * 6, 256, 0, stream>>>(
            (const unsigned short*)actb, (const unsigned short*)WcvT, res1, nullptr, bh, EQ, 6);

        ln_kernel<<<MP, 256, 0, stream>>>(res1, ln2w + l * EQ, ln2b + l * EQ, actb);

        mgemm_pk<EPI_BIAS_GELU, 24><<<8 * 7 * 16, 256, 0, stream>>>(
            (const unsigned short*)actb, (const unsigned short*)W1T, ffh, b1 + l * FQ, nullptr, FQ, 16);
        mgemm_pk<EPI_BIAS_RES, 64><<<8 * 7 * 6, 256, 0, stream>>>(
            (const unsigned short*)ffh, (const unsigned short*)W2T, bh, b2 + l * EQ, res1, EQ, 6);
    }
    logits_kernel<<<dim3(4, BQ), 256, 0, stream>>>(bh, Wc, bc, logit);
    smax_kernel<<<BQ, 256, 0, stream>>>(logit, out);
}

// Round 10
// 1177.384 us; speedup vs baseline: 1.8634x; 1.0390x over previous
//
#include <hip/hip_runtime.h>
#include <hip/hip_bf16.h>
#include <math.h>

#define BQ 32
#define SQ 197
#define EQ 768
#define HQ 12
#define DHQ 64
#define FQ 2048
#define LQ 4
#define CQ 1000
#define BSQ (BQ*SQ)     // 6304
#define SP 208          // padded rows per batch (13 * 16)
#define S16 13          // 16-row tiles per batch
#define MP (BQ*SP)      // 6656 padded total rows
#define NRT 52          // 128-row tiles
#define QKV3 2304
#define KTP 7           // t-chunks of 32 (224) for packed P / staged V
#define LN_EPS 1e-5f

typedef __bf16 bf16x8 __attribute__((ext_vector_type(8)));
typedef float f32x4 __attribute__((ext_vector_type(4)));
typedef unsigned short u16x8 __attribute__((ext_vector_type(8)));

__device__ __forceinline__ __hip_bfloat16 tobf(float f) { return __float2bfloat16(f); }

// Packed fragment layout: chunk of 8 bf16 for (row-tile rt, k-tile kt, lane):
//   buf[pk(rt,KT,kt,lane)+e] <-> A[rt*16+(lane&15)][kt*32+(lane>>4)*8+e]
__device__ __forceinline__ size_t pk(int rt, int KT, int kt, int lane) {
    return (((size_t)rt * KT + kt) * 64 + (size_t)lane) * 8;
}

// sizes (elems)
#define QPK_SLAB (S16*2*512)            // per (b,h): 13 rt x 2 kt x 512
#define QPK_TOT  ((size_t)BQ*HQ*QPK_SLAB + 4096)
#define PPK_SLAB (S16*KTP*512)          // per (b,h): 13 rt x 7 kt x 512
#define PPK_TOT  ((size_t)BQ*HQ*PPK_SLAB + 16384)

// ---------------- copy x into padded residual stream ------------------------
__global__ __launch_bounds__(256) void copy_pad(const float* __restrict__ x,
    float* __restrict__ bh)
{
    int r = blockIdx.x;
    int b = r / SQ, s = r % SQ;
    const float* src = x + (size_t)r * EQ;
    float* dst = bh + ((size_t)b * SP + s) * EQ;
    int t = threadIdx.x;
    dst[t] = src[t];
    dst[t + 256] = src[t + 256];
    dst[t + 512] = src[t + 512];
}

// ---------------- transpose + convert + PACK weights ------------------------
__global__ __launch_bounds__(256) void tconv_pk(const float* __restrict__ in,
    unsigned short* __restrict__ out, int R, int C, int KT, size_t slab, int ntPerSlab)
{
    __shared__ float tile[64][65];
    const float* ip = in + (size_t)blockIdx.z * slab;
    int r0 = blockIdx.x * 64, c0 = blockIdx.y * 64;
    int t = threadIdx.x;
    int tc = t & 63, tr = t >> 6;
    #pragma unroll
    for (int p = 0; p < 16; ++p) {
        int r = p * 4 + tr;
        tile[r][tc] = ip[(size_t)(r0 + r) * C + c0 + tc];
    }
    __syncthreads();
    int ntb = blockIdx.z * ntPerSlab + (c0 >> 4);
    int ktb = r0 >> 5;
    #pragma unroll
    for (int p = 0; p < 2; ++p) {
        int cc = p * 256 + t;
        int lane = cc & 63, grp = cc >> 6;
        int ktl = grp & 1, ntl = grp >> 1;
        int er = ktl * 32 + (lane >> 4) * 8;
        int dc = ntl * 16 + (lane & 15);
        u16x8 v;
        #pragma unroll
        for (int e = 0; e < 8; ++e) {
            __hip_bfloat16 h = tobf(tile[er + e][dc]);
            v[e] = *(unsigned short*)&h;
        }
        *(u16x8*)(out + pk(ntb + ntl, KT, ktb + ktl, lane)) = v;
    }
}

// ---------------- LayerNorm: fp32 (padded rows) -> PACKED bf16 (KT=24) ------
__global__ __launch_bounds__(256) void ln_kernel(const float* __restrict__ in,
    const float* __restrict__ w, const float* __restrict__ b,
    __hip_bfloat16* __restrict__ out)
{
    int row = blockIdx.x;
    const float* x = in + (size_t)row * EQ;
    int t = threadIdx.x;
    float v0 = x[t];
    float v1 = x[t + 256];
    float v2 = x[t + 512];
    __shared__ float red[256];
    red[t] = v0 + v1 + v2;
    __syncthreads();
    for (int off = 128; off > 0; off >>= 1) {
        if (t < off) red[t] += red[t + off];
        __syncthreads();
    }
    float mu = red[0] * (1.0f / EQ);
    __syncthreads();
    float d0 = v0 - mu, d1 = v1 - mu, d2 = v2 - mu;
    red[t] = d0*d0 + d1*d1 + d2*d2;
    __syncthreads();
    for (int off = 128; off > 0; off >>= 1) {
        if (t < off) red[t] += red[t + off];
        __syncthreads();
    }
    float rs = rsqrtf(red[0] * (1.0f / EQ) + LN_EPS);
    int rt = row >> 4, rsl = row & 15;
    float n0 = d0 * rs * w[t]       + b[t];
    float n1 = d1 * rs * w[t + 256] + b[t + 256];
    float n2 = d2 * rs * w[t + 512] + b[t + 512];
    #pragma unroll
    for (int p = 0; p < 3; ++p) {
        int k = t + (p << 8);
        float val = p == 0 ? n0 : (p == 1 ? n1 : n2);
        int kt = k >> 5, lane = (((k >> 3) & 3) << 4) + rsl, e = k & 7;
        out[pk(rt, 24, kt, lane) + e] = tobf(val);
    }
}

// ---------------- packed MFMA GEMM core (no barriers in K-loop) -------------
enum { EPI_NONE = 0, EPI_RES = 1, EPI_BIAS_GELU = 2, EPI_BIAS_RES = 3 };

template<int EPI, int KT>
__global__ __launch_bounds__(256) void mgemm_pk(
    const unsigned short* __restrict__ Apk, const unsigned short* __restrict__ Bpk,
    void* __restrict__ Cm, const float* __restrict__ bias,
    const float* __restrict__ res, int N, int nNT)
{
    const int g = blockIdx.x & 7;
    const int sIdx = blockIdx.x >> 3;
    const int b0 = (NRT * g) >> 3, b1 = (NRT * (g + 1)) >> 3;
    const int colT = sIdx % nNT, rloc = sIdx / nNT;
    if (b0 + rloc >= b1) return;
    const int row0 = (b0 + rloc) << 7, col0 = colT << 7;

    const int tid = threadIdx.x;
    const int lane = tid & 63;
    const int w = tid >> 6;
    const int wr = w >> 1, wc = w & 1;
    const int l15 = lane & 15, quad = lane >> 4;
    const int rt0 = (row0 >> 4) + wr * 4;
    const int nt0 = (col0 >> 4) + wc * 4;

    f32x4 acc[4][4] = {};
    bf16x8 a[2][4], b[2][4];
    auto ld = [&](int buf, int kt) {
        #pragma unroll
        for (int i = 0; i < 4; ++i)
            a[buf][i] = *(const bf16x8*)(Apk + pk(rt0 + i, KT, kt, lane));
        #pragma unroll
        for (int j = 0; j < 4; ++j)
            b[buf][j] = *(const bf16x8*)(Bpk + pk(nt0 + j, KT, kt, lane));
    };
    ld(0, 0);
    #pragma unroll 2
    for (int kt = 0; kt < KT; ++kt) {
        int cur = kt & 1;
        if (kt + 1 < KT) ld(cur ^ 1, kt + 1);
        #pragma unroll
        for (int i = 0; i < 4; ++i)
            #pragma unroll
            for (int j = 0; j < 4; ++j)
                acc[i][j] = __builtin_amdgcn_mfma_f32_16x16x32_bf16(a[cur][i], b[cur][j], acc[i][j], 0, 0, 0);
    }

    if constexpr (EPI == EPI_BIAS_GELU) {
        __shared__ unsigned short Cs[128][136];
        #pragma unroll
        for (int j = 0; j < 4; ++j) {
            float bv = bias[col0 + wc * 64 + j * 16 + l15];
            #pragma unroll
            for (int i = 0; i < 4; ++i)
                #pragma unroll
                for (int rg = 0; rg < 4; ++rg) {
                    float v = acc[i][j][rg] + bv;
                    v = 0.5f * v * (1.0f + erff(v * 0.70710678118654752f));
                    __hip_bfloat16 h = tobf(v);
                    Cs[wr * 64 + i * 16 + quad * 4 + rg][wc * 64 + j * 16 + l15] =
                        *(unsigned short*)&h;
                }
        }
        __syncthreads();
        const int KT2 = N >> 5;
        #pragma unroll
        for (int p = 0; p < 8; ++p) {
            int cc = p * 256 + tid;
            int ln2 = cc & 63, grp = cc >> 6;
            int ktl = grp & 3, rtl = grp >> 2;
            int rowl = rtl * 16 + (ln2 & 15);
            u16x8 v;
            #pragma unroll
            for (int e = 0; e < 8; ++e)
                v[e] = Cs[rowl][ktl * 32 + (ln2 >> 4) * 8 + e];
            *(u16x8*)((unsigned short*)Cm + pk((row0 >> 4) + rtl, KT2, (col0 >> 5) + ktl, ln2)) = v;
        }
    } else {
        #pragma unroll
        for (int j = 0; j < 4; ++j) {
            int c = col0 + wc * 64 + j * 16 + l15;
            float bv = (EPI == EPI_BIAS_RES) ? bias[c] : 0.f;
            #pragma unroll
            for (int i = 0; i < 4; ++i)
                #pragma unroll
                for (int rg = 0; rg < 4; ++rg) {
                    int r = row0 + wr * 64 + i * 16 + quad * 4 + rg;
                    float v = acc[i][j][rg];
                    size_t idx = (size_t)r * N + c;
                    if (EPI == EPI_BIAS_RES) {
                        ((float*)Cm)[idx] = v + bv + res[idx];
                    } else if (EPI == EPI_RES) {
                        ((float*)Cm)[idx] = v + res[idx];
                    } else {
                        ((__hip_bfloat16*)Cm)[idx] = tobf(v);
                    }
                }
        }
    }
}

// ---------------- QKV GEMM: packed A/B, epilogue -> per-head q/k pk + vbuf --
__global__ __launch_bounds__(256) void mgemm_qkv(
    const unsigned short* __restrict__ Apk, const unsigned short* __restrict__ Bpk,
    unsigned short* __restrict__ qpk, unsigned short* __restrict__ kpk,
    unsigned short* __restrict__ vbuf)
{
    const int g = blockIdx.x & 7;
    const int sIdx = blockIdx.x >> 3;
    const int b0 = (NRT * g) >> 3, b1 = (NRT * (g + 1)) >> 3;
    const int colT = sIdx % 18, rloc = sIdx / 18;
    if (b0 + rloc >= b1) return;
    const int row0 = (b0 + rloc) << 7, col0 = colT << 7;

    const int tid = threadIdx.x;
    const int lane = tid & 63;
    const int w = tid >> 6;
    const int wr = w >> 1, wc = w & 1;
    const int l15 = lane & 15, quad = lane >> 4;
    const int rt0 = (row0 >> 4) + wr * 4;
    const int nt0 = (col0 >> 4) + wc * 4;

    f32x4 acc[4][4] = {};
    bf16x8 a[2][4], b[2][4];
    auto ld = [&](int buf, int kt) {
        #pragma unroll
        for (int i = 0; i < 4; ++i)
            a[buf][i] = *(const bf16x8*)(Apk + pk(rt0 + i, 24, kt, lane));
        #pragma unroll
        for (int j = 0; j < 4; ++j)
            b[buf][j] = *(const bf16x8*)(Bpk + pk(nt0 + j, 24, kt, lane));
    };
    ld(0, 0);
    #pragma unroll 2
    for (int kt = 0; kt < 24; ++kt) {
        int cur = kt & 1;
        if (kt + 1 < 24) ld(cur ^ 1, kt + 1);
        #pragma unroll
        for (int i = 0; i < 4; ++i)
            #pragma unroll
            for (int j = 0; j < 4; ++j)
                acc[i][j] = __builtin_amdgcn_mfma_f32_16x16x32_bf16(a[cur][i], b[cur][j], acc[i][j], 0, 0, 0);
    }

    __shared__ unsigned short Cs[128][136];
    #pragma unroll
    for (int j = 0; j < 4; ++j)
        #pragma unroll
        for (int i = 0; i < 4; ++i)
            #pragma unroll
            for (int rg = 0; rg < 4; ++rg) {
                __hip_bfloat16 h = tobf(acc[i][j][rg]);
                Cs[wr * 64 + i * 16 + quad * 4 + rg][wc * 64 + j * 16 + l15] =
                    *(unsigned short*)&h;
            }
    __syncthreads();

    const int treg = col0 >> 7;   // 0..5 q, 6..11 k, 12..17 v
    if (treg < 12) {
        unsigned short* dst = (treg < 6) ? qpk : kpk;
        const int h0 = ((col0 % 768) >> 6);
        #pragma unroll
        for (int p = 0; p < 8; ++p) {
            int cc = p * 256 + tid;
            int ln2 = cc & 63, grp = cc >> 6;
            int hl = grp & 1, kt = (grp >> 1) & 1, rtl = grp >> 2;
            int row16 = (row0 >> 4) + rtl;
            int bb = row16 / S16;
            int s16 = row16 - bb * S16;
            int h = h0 + hl;
            u16x8 v;
            #pragma unroll
            for (int e = 0; e < 8; ++e)
                v[e] = Cs[rtl * 16 + (ln2 & 15)][hl * 64 + kt * 32 + (ln2 >> 4) * 8 + e];
            *(u16x8*)(dst + ((((size_t)(bb * HQ + h) * S16 + s16) * 2 + kt) << 9) + ln2 * 8) = v;
        }
    } else {
        #pragma unroll
        for (int p = 0; p < 8; ++p) {
            int cc = p * 256 + tid;
            int row = cc >> 4, c8 = cc & 15;
            u16x8 v;
            #pragma unroll
            for (int e = 0; e < 8; ++e)
                v[e] = Cs[row][c8 * 8 + e];
            *(u16x8*)(vbuf + (size_t)(row0 + row) * EQ + (col0 - 1536) + c8 * 8) = v;
        }
    }
}

// ------------- fused scores+softmax: packed q/k in, packed P out ------------
__global__ __launch_bounds__(256) void attn_sm(
    const unsigned short* __restrict__ qpk, const unsigned short* __restrict__ kpk,
    unsigned short* __restrict__ Ppk)
{
    const int s0 = blockIdx.x * 64;
    const int bh = blockIdx.y;
    const int tid = threadIdx.x;
    const int w = tid >> 6;
    const int lane = tid & 63;
    const int l15 = lane & 15, quad = lane >> 4;
    __shared__ float redm[4][64], reds[4][64];
    __shared__ unsigned short Ps[64][264];

    const unsigned short* qs = qpk + (size_t)bh * QPK_SLAB;
    const unsigned short* ks = kpk + (size_t)bh * QPK_SLAB;

    f32x4 acc[4][4] = {};
    #pragma unroll
    for (int kk = 0; kk < 2; ++kk) {
        bf16x8 af[4], bfr[4];
        #pragma unroll
        for (int i = 0; i < 4; ++i)
            af[i] = *(const bf16x8*)(qs + ((((s0 >> 4) + i) * 2 + kk) << 9) + lane * 8);
        #pragma unroll
        for (int j = 0; j < 4; ++j)
            bfr[j] = *(const bf16x8*)(ks + (((w * 4 + j) * 2 + kk) << 9) + lane * 8);
        #pragma unroll
        for (int i = 0; i < 4; ++i)
            #pragma unroll
            for (int j = 0; j < 4; ++j)
                acc[i][j] = __builtin_amdgcn_mfma_f32_16x16x32_bf16(af[i], bfr[j], acc[i][j], 0, 0, 0);
    }

    const float scale = 0.07124704998790965f;  // 1/sqrt(197)
    float sc[4][4][4];
    #pragma unroll
    for (int i = 0; i < 4; ++i)
        #pragma unroll
        for (int j = 0; j < 4; ++j) {
            bool ok = (w * 64 + j * 16 + l15) < SQ;
            #pragma unroll
            for (int rg = 0; rg < 4; ++rg)
                sc[i][rg][j] = ok ? acc[i][j][rg] * scale : -1e30f;
        }

    #pragma unroll
    for (int i = 0; i < 4; ++i)
        #pragma unroll
        for (int rg = 0; rg < 4; ++rg) {
            float m = fmaxf(fmaxf(sc[i][rg][0], sc[i][rg][1]), fmaxf(sc[i][rg][2], sc[i][rg][3]));
            #pragma unroll
            for (int d = 1; d < 16; d <<= 1) m = fmaxf(m, __shfl_xor(m, d));
            if (l15 == 0) redm[w][i * 16 + quad * 4 + rg] = m;
        }
    __syncthreads();

    float tot[4][4];
    #pragma unroll
    for (int i = 0; i < 4; ++i)
        #pragma unroll
        for (int rg = 0; rg < 4; ++rg) {
            int row = i * 16 + quad * 4 + rg;
            float m = fmaxf(fmaxf(redm[0][row], redm[1][row]),
                            fmaxf(redm[2][row], redm[3][row]));
            float s = 0.f;
            #pragma unroll
            for (int j = 0; j < 4; ++j) {
                float e = expf(sc[i][rg][j] - m);
                sc[i][rg][j] = e;
                s += e;
            }
            #pragma unroll
            for (int d = 1; d < 16; d <<= 1) s += __shfl_xor(s, d);
            if (l15 == 0) reds[w][row] = s;
            tot[i][rg] = 0.f;
        }
    __syncthreads();

    #pragma unroll
    for (int i = 0; i < 4; ++i)
        #pragma unroll
        for (int rg = 0; rg < 4; ++rg) {
            int row = i * 16 + quad * 4 + rg;
            tot[i][rg] = reds[0][row] + reds[1][row] + reds[2][row] + reds[3][row];
        }

    // P -> LDS (t>=197 are exact zeros via masked exp), then pack coalesced
    #pragma unroll
    for (int i = 0; i < 4; ++i)
        #pragma unroll
        for (int rg = 0; rg < 4; ++rg) {
            float inv = 1.0f / tot[i][rg];
            #pragma unroll
            for (int j = 0; j < 4; ++j) {
                __hip_bfloat16 h = tobf(sc[i][rg][j] * inv);
                Ps[i * 16 + quad * 4 + rg][w * 64 + j * 16 + l15] = *(unsigned short*)&h;
            }
        }
    __syncthreads();

    unsigned short* pp = Ppk + (size_t)bh * PPK_SLAB;
    #pragma unroll
    for (int p = 0; p < 7; ++p) {
        int cc = p * 256 + tid;
        int ln2 = cc & 63, grp = cc >> 6;
        int ktl = grp % 7, rtl = grp / 7;
        int rt = (s0 >> 4) + rtl;
        if (rt < S16) {
            u16x8 v;
            #pragma unroll
            for (int e = 0; e < 8; ++e)
                v[e] = Ps[rtl * 16 + (ln2 & 15)][ktl * 32 + (ln2 >> 4) * 8 + e];
            *(u16x8*)(pp + (((size_t)rt * KTP + ktl) << 9) + ln2 * 8) = v;
        }
    }
}

// ------------- o = P @ V : packed P, V^T staged coalesced, packed o out -----
__global__ __launch_bounds__(256) void attv_mfma(
    const unsigned short* __restrict__ Ppk, const unsigned short* __restrict__ vbuf,
    unsigned short* __restrict__ opk)
{
    __shared__ unsigned short Vs[64][264];
    __shared__ unsigned short Cs[64][72];
    const int s0 = blockIdx.x * 64;
    const int bh = blockIdx.y;
    const int b = bh / HQ, h = bh % HQ;
    const int tid = threadIdx.x;
    const int w = tid >> 6, lane = tid & 63;
    const int wr = w >> 1, wc = w & 1;
    const int l15 = lane & 15, quad = lane >> 4;

    // stage V^T: coalesced reads (8 lines/wave), scatter to Vs[d][t]; t>=197 -> 0
    #pragma unroll
    for (int p = 0; p < 7; ++p) {
        int cc = p * 256 + tid;
        int d8 = cc & 7, t = cc >> 3;           // t 0..223
        u16x8 v;
        if (t < SQ) {
            v = *(const u16x8*)(vbuf + ((size_t)b * SP + t) * EQ + h * DHQ + d8 * 8);
        } else {
            for (int e = 0; e < 8; ++e) v[e] = 0;
        }
        #pragma unroll
        for (int e = 0; e < 8; ++e)
            Vs[d8 * 8 + e][t] = v[e];
    }
    __syncthreads();

    const unsigned short* pp = Ppk + (size_t)bh * PPK_SLAB;
    f32x4 acc[2][2] = {};
    #pragma unroll
    for (int kk = 0; kk < KTP; ++kk) {
        bf16x8 af[2], bfr[2];
        #pragma unroll
        for (int i = 0; i < 2; ++i)
            af[i] = *(const bf16x8*)(pp + ((((size_t)(s0 >> 4) + wr * 2 + i) * KTP + kk) << 9) + lane * 8);
        #pragma unroll
        for (int j = 0; j < 2; ++j)
            bfr[j] = *(const bf16x8*)&Vs[wc * 32 + j * 16 + l15][kk * 32 + quad * 8];
        #pragma unroll
        for (int i = 0; i < 2; ++i)
            #pragma unroll
            for (int j = 0; j < 2; ++j)
                acc[i][j] = __builtin_amdgcn_mfma_f32_16x16x32_bf16(af[i], bfr[j], acc[i][j], 0, 0, 0);
    }

    #pragma unroll
    for (int i = 0; i < 2; ++i)
        #pragma unroll
        for (int j = 0; j < 2; ++j)
            #pragma unroll
            for (int rg = 0; rg < 4; ++rg) {
                __hip_bfloat16 hv = tobf(acc[i][j][rg]);
                Cs[wr * 32 + i * 16 + quad * 4 + rg][wc * 32 + j * 16 + l15] =
                    *(unsigned short*)&hv;
            }
    __syncthreads();

    const int rt0 = b * S16 + (s0 >> 4);
    const int kt0 = h * 2;
    int validRt = (SP - s0) >> 4; if (validRt > 4) validRt = 4;
    #pragma unroll
    for (int p = 0; p < 2; ++p) {
        int cc = p * 256 + tid;
        int ln2 = cc & 63, grp = cc >> 6;
        int ktl = grp & 1, rtl = grp >> 1;
        if (rtl < validRt) {
            int rowl = rtl * 16 + (ln2 & 15);
            int colb = ktl * 32 + (ln2 >> 4) * 8;
            u16x8 v;
            #pragma unroll
            for (int e = 0; e < 8; ++e)
                v[e] = Cs[rowl][colb + e];
            *(u16x8*)(opk + pk(rt0 + rtl, 24, kt0 + ktl, ln2)) = v;
        }
    }
}

// ---------------- classifier: split-K logits + softmax ----------------------
__global__ __launch_bounds__(256) void logits_kernel(
    const float* __restrict__ hbuf, const float* __restrict__ Wc,
    const float* __restrict__ bc, float* __restrict__ logits)
{
    __shared__ __align__(16) float hs[768];
    __shared__ float red[256];
    int b = blockIdx.y;
    int tid = threadIdx.x;
    const float* hr = hbuf + (size_t)b * SP * EQ;   // s=0 row
    for (int p = tid; p < 192; p += 256)
        *(float4*)&hs[p << 2] = *(const float4*)(hr + (p << 2));
    __syncthreads();
    int cl = tid & 31, ks = tid >> 5;
    int c = blockIdx.x * 32 + cl;
    int cs = (c < CQ) ? c : 0;
    float s = 0.f;
    int e0 = ks * 96;
    #pragma unroll 8
    for (int e = 0; e < 96; ++e)
        s = fmaf(hs[e0 + e], Wc[(size_t)(e0 + e) * CQ + cs], s);
    red[tid] = s;
    __syncthreads();
    for (int off = 128; off >= 32; off >>= 1) {
        if (tid < off) red[tid] += red[tid + off];
        __syncthreads();
    }
    if (tid < 32 && c < CQ)
        logits[(size_t)b * CQ + c] = red[tid] + bc[c];
}

__global__ __launch_bounds__(256) void smax_kernel(
    const float* __restrict__ logits, float* __restrict__ out)
{
    __shared__ float red[256];
    int b = blockIdx.x;
    int t = threadIdx.x;
    const float* lp = logits + (size_t)b * CQ;
    float lg[4];
    #pragma unroll
    for (int j = 0; j < 4; ++j) {
        int c = t + j * 256;
        lg[j] = (c < CQ) ? lp[c] : -1e30f;
    }
    float m = fmaxf(fmaxf(lg[0], lg[1]), fmaxf(lg[2], lg[3]));
    red[t] = m;
    __syncthreads();
    for (int off = 128; off; off >>= 1) {
        if (t < off) red[t] = fmaxf(red[t], red[t + off]);
        __syncthreads();
    }
    m = red[0];
    __syncthreads();
    float ex[4], s = 0.f;
    #pragma unroll
    for (int j = 0; j < 4; ++j) {
        ex[j] = (t + j * 256 < CQ) ? expf(lg[j] - m) : 0.f;
        s += ex[j];
    }
    red[t] = s;
    __syncthreads();
    for (int off = 128; off; off >>= 1) {
        if (t < off) red[t] += red[t + off];
        __syncthreads();
    }
    float inv = 1.0f / red[0];
    #pragma unroll
    for (int j = 0; j < 4; ++j)
        if (t + j * 256 < CQ) out[(size_t)b * CQ + t + j * 256] = ex[j] * inv;
}

extern "C" void kernel_launch(void* const* d_in, const int* in_sizes, int n_in,
                              void* d_out, int out_size, void* d_ws, size_t ws_size,
                              hipStream_t stream)
{
    const float* x     = (const float*)d_in[0];
    const float* Wk    = (const float*)d_in[1];
    const float* Wq    = (const float*)d_in[2];
    const float* Wv    = (const float*)d_in[3];
    const float* Wconv = (const float*)d_in[4];
    const float* ln1w  = (const float*)d_in[5];
    const float* ln1b  = (const float*)d_in[6];
    const float* ln2w  = (const float*)d_in[7];
    const float* ln2b  = (const float*)d_in[8];
    const float* W1    = (const float*)d_in[9];
    const float* b1    = (const float*)d_in[10];
    const float* W2    = (const float*)d_in[11];
    const float* b2    = (const float*)d_in[12];
    const float* Wc    = (const float*)d_in[13];
    const float* bc    = (const float*)d_in[14];
    float* out = (float*)d_out;

    const size_t MPE = (size_t)MP * EQ;

    float* w = (float*)d_ws;
    float* bh    = w; w += MPE;
    float* res1  = w; w += MPE;
    float* logit = w; w += (size_t)BQ * CQ;
    unsigned short* qpk  = (unsigned short*)w;
    unsigned short* kpk  = qpk + QPK_TOT;
    unsigned short* vbuf = kpk + QPK_TOT;
    unsigned short* actb = vbuf + MPE;              // packed activations
    unsigned short* Ppk  = actb + MPE;
    unsigned short* wbuf = Ppk + PPK_TOT;
    unsigned short* ffh  = Ppk;                     // FF hidden overlays Ppk

    const size_t WQKV = (size_t)EQ * EQ;
    unsigned short* WqT  = wbuf;
    unsigned short* WkT  = wbuf + WQKV;
    unsigned short* WvT  = wbuf + 2 * WQKV;
    unsigned short* WcvT = wbuf;                    // phase B overlays
    unsigned short* W1T  = wbuf + WQKV;
    unsigned short* W2T  = W1T + (size_t)EQ * FQ;

    copy_pad<<<BSQ, 256, 0, stream>>>(x, bh);

    for (int l = 0; l < LQ; ++l) {
        tconv_pk<<<dim3(12, 1, HQ), 256, 0, stream>>>(Wq + (size_t)l * HQ * EQ * DHQ, WqT, EQ, DHQ, 24, (size_t)EQ * DHQ, 4);
        tconv_pk<<<dim3(12, 1, HQ), 256, 0, stream>>>(Wk + (size_t)l * HQ * EQ * DHQ, WkT, EQ, DHQ, 24, (size_t)EQ * DHQ, 4);
        tconv_pk<<<dim3(12, 1, HQ), 256, 0, stream>>>(Wv + (size_t)l * HQ * EQ * DHQ, WvT, EQ, DHQ, 24, (size_t)EQ * DHQ, 4);

        ln_kernel<<<MP, 256, 0, stream>>>(bh, ln1w + l * EQ, ln1b + l * EQ, (__hip_bfloat16*)actb);

        mgemm_qkv<<<8 * 7 * 18, 256, 0, stream>>>(actb, wbuf, qpk, kpk, vbuf);

        tconv_pk<<<dim3(12, 12, 1), 256, 0, stream>>>(Wconv + (size_t)l * EQ * EQ, WcvT, EQ, EQ, 24, 0, 0);
        tconv_pk<<<dim3(12, 32, 1), 256, 0, stream>>>(W1 + (size_t)l * EQ * FQ, W1T, EQ, FQ, 24, 0, 0);
        tconv_pk<<<dim3(32, 12, 1), 256, 0, stream>>>(W2 + (size_t)l * FQ * EQ, W2T, FQ, EQ, 64, 0, 0);

        attn_sm<<<dim3(4, BQ * HQ), 256, 0, stream>>>(qpk, kpk, Ppk);
        attv_mfma<<<dim3(4, BQ * HQ), 256, 0, stream>>>(Ppk, vbuf, actb);

        mgemm_pk<EPI_RES, 24><<<8 * 7 * 6, 256, 0, stream>>>(
            actb, WcvT, res1, nullptr, bh, EQ, 6);

        ln_kernel<<<MP, 256, 0, stream>>>(res1, ln2w + l * EQ, ln2b + l * EQ, (__hip_bfloat16*)actb);

        mgemm_pk<EPI_BIAS_GELU, 24><<<8 * 7 * 16, 256, 0, stream>>>(
            actb, W1T, ffh, b1 + l * FQ, nullptr, FQ, 16);
        mgemm_pk<EPI_BIAS_RES, 64><<<8 * 7 * 6, 256, 0, stream>>>(
            ffh, W2T, bh, b2 + l * EQ, res1, EQ, 6);
    }
    logits_kernel<<<dim3(32, BQ), 256, 0, stream>>>(bh, Wc, bc, logit);
    smax_kernel<<<BQ, 256, 0, stream>>>(logit, out);
}

// Round 11
// 1135.906 us; speedup vs baseline: 1.9314x; 1.0365x over previous
//
#include <hip/hip_runtime.h>
#include <hip/hip_bf16.h>
#include <math.h>

#define BQ 32
#define SQ 197
#define EQ 768
#define HQ 12
#define DHQ 64
#define FQ 2048
#define LQ 4
#define CQ 1000
#define BSQ (BQ*SQ)     // 6304
#define SP 208          // padded rows per batch (13 * 16)
#define S16 13          // 16-row tiles per batch
#define MP (BQ*SP)      // 6656 padded total rows
#define QKV3 2304
#define KTP 7           // t-chunks of 32 (224) for P / staged V
#define LN_EPS 1e-5f

typedef __bf16 bf16x8 __attribute__((ext_vector_type(8)));
typedef float f32x4 __attribute__((ext_vector_type(4)));
typedef unsigned short u16x8 __attribute__((ext_vector_type(8)));

__device__ __forceinline__ __hip_bfloat16 tobf(float f) { return __float2bfloat16(f); }

// Packed fragment layout: chunk of 8 bf16 for (row-tile rt, k-tile kt, lane):
//   buf[pk(rt,KT,kt,lane)+e] <-> A[rt*16+(lane&15)][kt*32+(lane>>4)*8+e]
__device__ __forceinline__ size_t pk(int rt, int KT, int kt, int lane) {
    return (((size_t)rt * KT + kt) * 64 + (size_t)lane) * 8;
}

// sizes (elems)
#define QPK_SLAB (S16*2*512)            // per (b,h): 13 rt x 2 kt x 512
#define QPK_TOT  ((size_t)BQ*HQ*QPK_SLAB + 4096)

// ---------------- copy x into padded residual stream ------------------------
__global__ __launch_bounds__(256) void copy_pad(const float* __restrict__ x,
    float* __restrict__ bh)
{
    int r = blockIdx.x;
    int b = r / SQ, s = r % SQ;
    const float* src = x + (size_t)r * EQ;
    float* dst = bh + ((size_t)b * SP + s) * EQ;
    int t = threadIdx.x;
    dst[t] = src[t];
    dst[t + 256] = src[t + 256];
    dst[t + 512] = src[t + 512];
}

// ---------------- transpose + convert + PACK weights ------------------------
__global__ __launch_bounds__(256) void tconv_pk(const float* __restrict__ in,
    unsigned short* __restrict__ out, int R, int C, int KT, size_t slab, int ntPerSlab)
{
    __shared__ float tile[64][65];
    const float* ip = in + (size_t)blockIdx.z * slab;
    int r0 = blockIdx.x * 64, c0 = blockIdx.y * 64;
    int t = threadIdx.x;
    int tc = t & 63, tr = t >> 6;
    #pragma unroll
    for (int p = 0; p < 16; ++p) {
        int r = p * 4 + tr;
        tile[r][tc] = ip[(size_t)(r0 + r) * C + c0 + tc];
    }
    __syncthreads();
    int ntb = blockIdx.z * ntPerSlab + (c0 >> 4);
    int ktb = r0 >> 5;
    #pragma unroll
    for (int p = 0; p < 2; ++p) {
        int cc = p * 256 + t;
        int lane = cc & 63, grp = cc >> 6;
        int ktl = grp & 1, ntl = grp >> 1;
        int er = ktl * 32 + (lane >> 4) * 8;
        int dc = ntl * 16 + (lane & 15);
        u16x8 v;
        #pragma unroll
        for (int e = 0; e < 8; ++e) {
            __hip_bfloat16 h = tobf(tile[er + e][dc]);
            v[e] = *(unsigned short*)&h;
        }
        *(u16x8*)(out + pk(ntb + ntl, KT, ktb + ktl, lane)) = v;
    }
}

// ---------------- LayerNorm: fp32 (padded rows) -> PACKED bf16 (KT=24) ------
__global__ __launch_bounds__(256) void ln_kernel(const float* __restrict__ in,
    const float* __restrict__ w, const float* __restrict__ b,
    __hip_bfloat16* __restrict__ out)
{
    int row = blockIdx.x;
    const float* x = in + (size_t)row * EQ;
    int t = threadIdx.x;
    float v0 = x[t];
    float v1 = x[t + 256];
    float v2 = x[t + 512];
    __shared__ float red[256];
    red[t] = v0 + v1 + v2;
    __syncthreads();
    for (int off = 128; off > 0; off >>= 1) {
        if (t < off) red[t] += red[t + off];
        __syncthreads();
    }
    float mu = red[0] * (1.0f / EQ);
    __syncthreads();
    float d0 = v0 - mu, d1 = v1 - mu, d2 = v2 - mu;
    red[t] = d0*d0 + d1*d1 + d2*d2;
    __syncthreads();
    for (int off = 128; off > 0; off >>= 1) {
        if (t < off) red[t] += red[t + off];
        __syncthreads();
    }
    float rs = rsqrtf(red[0] * (1.0f / EQ) + LN_EPS);
    int rt = row >> 4, rsl = row & 15;
    float n0 = d0 * rs * w[t]       + b[t];
    float n1 = d1 * rs * w[t + 256] + b[t + 256];
    float n2 = d2 * rs * w[t + 512] + b[t + 512];
    #pragma unroll
    for (int p = 0; p < 3; ++p) {
        int k = t + (p << 8);
        float val = p == 0 ? n0 : (p == 1 ? n1 : n2);
        int kt = k >> 5, lane = (((k >> 3) & 3) << 4) + rsl, e = k & 7;
        out[pk(rt, 24, kt, lane) + e] = tobf(val);
    }
}

// ---------------- packed MFMA GEMM core (no barriers in K-loop) -------------
// RT = row-tiles (16 rows) per wave: 4 -> 128-row block tile, 2 -> 64-row.
enum { EPI_NONE = 0, EPI_RES = 1, EPI_BIAS_GELU = 2, EPI_BIAS_RES = 3 };

template<int EPI, int KT, int RT>
__global__ __launch_bounds__(256) void mgemm_pk(
    const unsigned short* __restrict__ Apk, const unsigned short* __restrict__ Bpk,
    void* __restrict__ Cm, const float* __restrict__ bias,
    const float* __restrict__ res, int N, int nNT)
{
    const int nRowT = (RT == 4) ? 52 : 104;        // MP/ (RT*32)
    const int g = blockIdx.x & 7;
    const int sIdx = blockIdx.x >> 3;
    const int b0 = (nRowT * g) >> 3, b1 = (nRowT * (g + 1)) >> 3;
    const int colT = sIdx % nNT, rloc = sIdx / nNT;
    if (b0 + rloc >= b1) return;
    const int row0 = (b0 + rloc) * (RT * 32), col0 = colT << 7;

    const int tid = threadIdx.x;
    const int lane = tid & 63;
    const int w = tid >> 6;
    const int wr = w >> 1, wc = w & 1;
    const int l15 = lane & 15, quad = lane >> 4;
    const int rt0 = (row0 >> 4) + wr * RT;
    const int nt0 = (col0 >> 4) + wc * 4;

    f32x4 acc[RT][4] = {};
    bf16x8 a[2][RT], b[2][4];
    auto ld = [&](int buf, int kt) {
        #pragma unroll
        for (int i = 0; i < RT; ++i)
            a[buf][i] = *(const bf16x8*)(Apk + pk(rt0 + i, KT, kt, lane));
        #pragma unroll
        for (int j = 0; j < 4; ++j)
            b[buf][j] = *(const bf16x8*)(Bpk + pk(nt0 + j, KT, kt, lane));
    };
    ld(0, 0);
    #pragma unroll 2
    for (int kt = 0; kt < KT; ++kt) {
        int cur = kt & 1;
        if (kt + 1 < KT) ld(cur ^ 1, kt + 1);
        #pragma unroll
        for (int i = 0; i < RT; ++i)
            #pragma unroll
            for (int j = 0; j < 4; ++j)
                acc[i][j] = __builtin_amdgcn_mfma_f32_16x16x32_bf16(a[cur][i], b[cur][j], acc[i][j], 0, 0, 0);
    }

    if constexpr (EPI == EPI_BIAS_GELU) {
        // RT==4 only: C written PACKED (next GEMM's A)
        __shared__ unsigned short Cs[128][136];
        #pragma unroll
        for (int j = 0; j < 4; ++j) {
            float bv = bias[col0 + wc * 64 + j * 16 + l15];
            #pragma unroll
            for (int i = 0; i < RT; ++i)
                #pragma unroll
                for (int rg = 0; rg < 4; ++rg) {
                    float v = acc[i][j][rg] + bv;
                    v = 0.5f * v * (1.0f + erff(v * 0.70710678118654752f));
                    __hip_bfloat16 h = tobf(v);
                    Cs[wr * 64 + i * 16 + quad * 4 + rg][wc * 64 + j * 16 + l15] =
                        *(unsigned short*)&h;
                }
        }
        __syncthreads();
        const int KT2 = N >> 5;
        #pragma unroll
        for (int p = 0; p < 8; ++p) {
            int cc = p * 256 + tid;
            int ln2 = cc & 63, grp = cc >> 6;
            int ktl = grp & 3, rtl = grp >> 2;
            int rowl = rtl * 16 + (ln2 & 15);
            u16x8 v;
            #pragma unroll
            for (int e = 0; e < 8; ++e)
                v[e] = Cs[rowl][ktl * 32 + (ln2 >> 4) * 8 + e];
            *(u16x8*)((unsigned short*)Cm + pk((row0 >> 4) + rtl, KT2, (col0 >> 5) + ktl, ln2)) = v;
        }
    } else {
        #pragma unroll
        for (int j = 0; j < 4; ++j) {
            int c = col0 + wc * 64 + j * 16 + l15;
            float bv = (EPI == EPI_BIAS_RES) ? bias[c] : 0.f;
            #pragma unroll
            for (int i = 0; i < RT; ++i)
                #pragma unroll
                for (int rg = 0; rg < 4; ++rg) {
                    int r = row0 + wr * (RT * 16) + i * 16 + quad * 4 + rg;
                    float v = acc[i][j][rg];
                    size_t idx = (size_t)r * N + c;
                    if (EPI == EPI_BIAS_RES) {
                        ((float*)Cm)[idx] = v + bv + res[idx];
                    } else if (EPI == EPI_RES) {
                        ((float*)Cm)[idx] = v + res[idx];
                    } else {
                        ((__hip_bfloat16*)Cm)[idx] = tobf(v);
                    }
                }
        }
    }
}

// ---------------- QKV GEMM: packed A/B, epilogue -> per-head q/k pk + vbuf --
__global__ __launch_bounds__(256) void mgemm_qkv(
    const unsigned short* __restrict__ Apk, const unsigned short* __restrict__ Bpk,
    unsigned short* __restrict__ qpk, unsigned short* __restrict__ kpk,
    unsigned short* __restrict__ vbuf)
{
    const int g = blockIdx.x & 7;
    const int sIdx = blockIdx.x >> 3;
    const int b0 = (52 * g) >> 3, b1 = (52 * (g + 1)) >> 3;
    const int colT = sIdx % 18, rloc = sIdx / 18;
    if (b0 + rloc >= b1) return;
    const int row0 = (b0 + rloc) << 7, col0 = colT << 7;

    const int tid = threadIdx.x;
    const int lane = tid & 63;
    const int w = tid >> 6;
    const int wr = w >> 1, wc = w & 1;
    const int l15 = lane & 15, quad = lane >> 4;
    const int rt0 = (row0 >> 4) + wr * 4;
    const int nt0 = (col0 >> 4) + wc * 4;

    f32x4 acc[4][4] = {};
    bf16x8 a[2][4], b[2][4];
    auto ld = [&](int buf, int kt) {
        #pragma unroll
        for (int i = 0; i < 4; ++i)
            a[buf][i] = *(const bf16x8*)(Apk + pk(rt0 + i, 24, kt, lane));
        #pragma unroll
        for (int j = 0; j < 4; ++j)
            b[buf][j] = *(const bf16x8*)(Bpk + pk(nt0 + j, 24, kt, lane));
    };
    ld(0, 0);
    #pragma unroll 2
    for (int kt = 0; kt < 24; ++kt) {
        int cur = kt & 1;
        if (kt + 1 < 24) ld(cur ^ 1, kt + 1);
        #pragma unroll
        for (int i = 0; i < 4; ++i)
            #pragma unroll
            for (int j = 0; j < 4; ++j)
                acc[i][j] = __builtin_amdgcn_mfma_f32_16x16x32_bf16(a[cur][i], b[cur][j], acc[i][j], 0, 0, 0);
    }

    __shared__ unsigned short Cs[128][136];
    #pragma unroll
    for (int j = 0; j < 4; ++j)
        #pragma unroll
        for (int i = 0; i < 4; ++i)
            #pragma unroll
            for (int rg = 0; rg < 4; ++rg) {
                __hip_bfloat16 h = tobf(acc[i][j][rg]);
                Cs[wr * 64 + i * 16 + quad * 4 + rg][wc * 64 + j * 16 + l15] =
                    *(unsigned short*)&h;
            }
    __syncthreads();

    const int treg = col0 >> 7;   // 0..5 q, 6..11 k, 12..17 v
    if (treg < 12) {
        unsigned short* dst = (treg < 6) ? qpk : kpk;
        const int h0 = ((col0 % 768) >> 6);
        #pragma unroll
        for (int p = 0; p < 8; ++p) {
            int cc = p * 256 + tid;
            int ln2 = cc & 63, grp = cc >> 6;
            int hl = grp & 1, kt = (grp >> 1) & 1, rtl = grp >> 2;
            int row16 = (row0 >> 4) + rtl;
            int bb = row16 / S16;
            int s16 = row16 - bb * S16;
            int h = h0 + hl;
            u16x8 v;
            #pragma unroll
            for (int e = 0; e < 8; ++e)
                v[e] = Cs[rtl * 16 + (ln2 & 15)][hl * 64 + kt * 32 + (ln2 >> 4) * 8 + e];
            *(u16x8*)(dst + ((((size_t)(bb * HQ + h) * S16 + s16) * 2 + kt) << 9) + ln2 * 8) = v;
        }
    } else {
        #pragma unroll
        for (int p = 0; p < 8; ++p) {
            int cc = p * 256 + tid;
            int row = cc >> 4, c8 = cc & 15;
            u16x8 v;
            #pragma unroll
            for (int e = 0; e < 8; ++e)
                v[e] = Cs[row][c8 * 8 + e];
            *(u16x8*)(vbuf + (size_t)(row0 + row) * EQ + (col0 - 1536) + c8 * 8) = v;
        }
    }
}

// ------------- FUSED attention: scores+softmax -> P in LDS -> P@V -> o pk ---
__global__ __launch_bounds__(256) void attn_fused(
    const unsigned short* __restrict__ qpk, const unsigned short* __restrict__ kpk,
    const unsigned short* __restrict__ vbuf, unsigned short* __restrict__ opk)
{
    __shared__ float redm[4][64], reds[4][64];
    __shared__ unsigned short Ps[64][264];
    __shared__ unsigned short Vs[64][264];
    __shared__ unsigned short Cs[64][72];
    const int s0 = blockIdx.x * 64;
    const int bh = blockIdx.y;
    const int b = bh / HQ, h = bh % HQ;
    const int tid = threadIdx.x;
    const int w = tid >> 6, lane = tid & 63;
    const int wr = w >> 1, wc = w & 1;
    const int l15 = lane & 15, quad = lane >> 4;

    // front-issue V loads; latency shadowed by the score phase below
    u16x8 vt[7];
    #pragma unroll
    for (int p = 0; p < 7; ++p) {
        int cc = p * 256 + tid;
        int d8 = cc & 7, t = cc >> 3;           // t 0..223
        if (t < SQ) {
            vt[p] = *(const u16x8*)(vbuf + ((size_t)b * SP + t) * EQ + h * DHQ + d8 * 8);
        } else {
            for (int e = 0; e < 8; ++e) vt[p][e] = 0;
        }
    }

    const unsigned short* qs = qpk + (size_t)bh * QPK_SLAB;
    const unsigned short* ks = kpk + (size_t)bh * QPK_SLAB;

    f32x4 acc[4][4] = {};
    #pragma unroll
    for (int kk = 0; kk < 2; ++kk) {
        bf16x8 af[4], bfr[4];
        #pragma unroll
        for (int i = 0; i < 4; ++i)
            af[i] = *(const bf16x8*)(qs + ((((s0 >> 4) + i) * 2 + kk) << 9) + lane * 8);
        #pragma unroll
        for (int j = 0; j < 4; ++j)
            bfr[j] = *(const bf16x8*)(ks + (((w * 4 + j) * 2 + kk) << 9) + lane * 8);
        #pragma unroll
        for (int i = 0; i < 4; ++i)
            #pragma unroll
            for (int j = 0; j < 4; ++j)
                acc[i][j] = __builtin_amdgcn_mfma_f32_16x16x32_bf16(af[i], bfr[j], acc[i][j], 0, 0, 0);
    }

    const float scale = 0.07124704998790965f;  // 1/sqrt(197)
    float sc[4][4][4];
    #pragma unroll
    for (int i = 0; i < 4; ++i)
        #pragma unroll
        for (int j = 0; j < 4; ++j) {
            bool ok = (w * 64 + j * 16 + l15) < SQ;
            #pragma unroll
            for (int rg = 0; rg < 4; ++rg)
                sc[i][rg][j] = ok ? acc[i][j][rg] * scale : -1e30f;
        }

    #pragma unroll
    for (int i = 0; i < 4; ++i)
        #pragma unroll
        for (int rg = 0; rg < 4; ++rg) {
            float m = fmaxf(fmaxf(sc[i][rg][0], sc[i][rg][1]), fmaxf(sc[i][rg][2], sc[i][rg][3]));
            #pragma unroll
            for (int d = 1; d < 16; d <<= 1) m = fmaxf(m, __shfl_xor(m, d));
            if (l15 == 0) redm[w][i * 16 + quad * 4 + rg] = m;
        }
    __syncthreads();

    float tot[4][4];
    #pragma unroll
    for (int i = 0; i < 4; ++i)
        #pragma unroll
        for (int rg = 0; rg < 4; ++rg) {
            int row = i * 16 + quad * 4 + rg;
            float m = fmaxf(fmaxf(redm[0][row], redm[1][row]),
                            fmaxf(redm[2][row], redm[3][row]));
            float s = 0.f;
            #pragma unroll
            for (int j = 0; j < 4; ++j) {
                float e = expf(sc[i][rg][j] - m);
                sc[i][rg][j] = e;
                s += e;
            }
            #pragma unroll
            for (int d = 1; d < 16; d <<= 1) s += __shfl_xor(s, d);
            if (l15 == 0) reds[w][row] = s;
            tot[i][rg] = 0.f;
        }
    __syncthreads();

    #pragma unroll
    for (int i = 0; i < 4; ++i)
        #pragma unroll
        for (int rg = 0; rg < 4; ++rg) {
            int row = i * 16 + quad * 4 + rg;
            tot[i][rg] = reds[0][row] + reds[1][row] + reds[2][row] + reds[3][row];
        }

    // normalized P -> LDS (cols >=197 are exact zeros via masked exp)
    #pragma unroll
    for (int i = 0; i < 4; ++i)
        #pragma unroll
        for (int rg = 0; rg < 4; ++rg) {
            float inv = 1.0f / tot[i][rg];
            #pragma unroll
            for (int j = 0; j < 4; ++j) {
                __hip_bfloat16 hv = tobf(sc[i][rg][j] * inv);
                Ps[i * 16 + quad * 4 + rg][w * 64 + j * 16 + l15] = *(unsigned short*)&hv;
            }
        }

    // V -> LDS (loads long since landed)
    #pragma unroll
    for (int p = 0; p < 7; ++p) {
        int cc = p * 256 + tid;
        int d8 = cc & 7, t = cc >> 3;
        #pragma unroll
        for (int e = 0; e < 8; ++e)
            Vs[d8 * 8 + e][t] = vt[p][e];
    }
    __syncthreads();

    // P @ V
    f32x4 av[2][2] = {};
    #pragma unroll
    for (int kk = 0; kk < KTP; ++kk) {
        bf16x8 af[2], bfr[2];
        #pragma unroll
        for (int i = 0; i < 2; ++i)
            af[i] = *(const bf16x8*)&Ps[wr * 32 + i * 16 + l15][kk * 32 + quad * 8];
        #pragma unroll
        for (int j = 0; j < 2; ++j)
            bfr[j] = *(const bf16x8*)&Vs[wc * 32 + j * 16 + l15][kk * 32 + quad * 8];
        #pragma unroll
        for (int i = 0; i < 2; ++i)
            #pragma unroll
            for (int j = 0; j < 2; ++j)
                av[i][j] = __builtin_amdgcn_mfma_f32_16x16x32_bf16(af[i], bfr[j], av[i][j], 0, 0, 0);
    }

    #pragma unroll
    for (int i = 0; i < 2; ++i)
        #pragma unroll
        for (int j = 0; j < 2; ++j)
            #pragma unroll
            for (int rg = 0; rg < 4; ++rg) {
                __hip_bfloat16 hv = tobf(av[i][j][rg]);
                Cs[wr * 32 + i * 16 + quad * 4 + rg][wc * 32 + j * 16 + l15] =
                    *(unsigned short*)&hv;
            }
    __syncthreads();

    const int rt0 = b * S16 + (s0 >> 4);
    const int kt0 = h * 2;
    int validRt = (SP - s0) >> 4; if (validRt > 4) validRt = 4;
    #pragma unroll
    for (int p = 0; p < 2; ++p) {
        int cc = p * 256 + tid;
        int ln2 = cc & 63, grp = cc >> 6;
        int ktl = grp & 1, rtl = grp >> 1;
        if (rtl < validRt) {
            int rowl = rtl * 16 + (ln2 & 15);
            int colb = ktl * 32 + (ln2 >> 4) * 8;
            u16x8 v;
            #pragma unroll
            for (int e = 0; e < 8; ++e)
                v[e] = Cs[rowl][colb + e];
            *(u16x8*)(opk + pk(rt0 + rtl, 24, kt0 + ktl, ln2)) = v;
        }
    }
}

// ---------------- classifier: split-K logits + softmax ----------------------
__global__ __launch_bounds__(256) void logits_kernel(
    const float* __restrict__ hbuf, const float* __restrict__ Wc,
    const float* __restrict__ bc, float* __restrict__ logits)
{
    __shared__ __align__(16) float hs[768];
    __shared__ float red[256];
    int b = blockIdx.y;
    int tid = threadIdx.x;
    const float* hr = hbuf + (size_t)b * SP * EQ;   // s=0 row
    for (int p = tid; p < 192; p += 256)
        *(float4*)&hs[p << 2] = *(const float4*)(hr + (p << 2));
    __syncthreads();
    int cl = tid & 31, ks = tid >> 5;
    int c = blockIdx.x * 32 + cl;
    int cs = (c < CQ) ? c : 0;
    float s = 0.f;
    int e0 = ks * 96;
    #pragma unroll 8
    for (int e = 0; e < 96; ++e)
        s = fmaf(hs[e0 + e], Wc[(size_t)(e0 + e) * CQ + cs], s);
    red[tid] = s;
    __syncthreads();
    for (int off = 128; off >= 32; off >>= 1) {
        if (tid < off) red[tid] += red[tid + off];
        __syncthreads();
    }
    if (tid < 32 && c < CQ)
        logits[(size_t)b * CQ + c] = red[tid] + bc[c];
}

__global__ __launch_bounds__(256) void smax_kernel(
    const float* __restrict__ logits, float* __restrict__ out)
{
    __shared__ float red[256];
    int b = blockIdx.x;
    int t = threadIdx.x;
    const float* lp = logits + (size_t)b * CQ;
    float lg[4];
    #pragma unroll
    for (int j = 0; j < 4; ++j) {
        int c = t + j * 256;
        lg[j] = (c < CQ) ? lp[c] : -1e30f;
    }
    float m = fmaxf(fmaxf(lg[0], lg[1]), fmaxf(lg[2], lg[3]));
    red[t] = m;
    __syncthreads();
    for (int off = 128; off; off >>= 1) {
        if (t < off) red[t] = fmaxf(red[t], red[t + off]);
        __syncthreads();
    }
    m = red[0];
    __syncthreads();
    float ex[4], s = 0.f;
    #pragma unroll
    for (int j = 0; j < 4; ++j) {
        ex[j] = (t + j * 256 < CQ) ? expf(lg[j] - m) : 0.f;
        s += ex[j];
    }
    red[t] = s;
    __syncthreads();
    for (int off = 128; off; off >>= 1) {
        if (t < off) red[t] += red[t + off];
        __syncthreads();
    }
    float inv = 1.0f / red[0];
    #pragma unroll
    for (int j = 0; j < 4; ++j)
        if (t + j * 256 < CQ) out[(size_t)b * CQ + t + j * 256] = ex[j] * inv;
}

extern "C" void kernel_launch(void* const* d_in, const int* in_sizes, int n_in,
                              void* d_out, int out_size, void* d_ws, size_t ws_size,
                              hipStream_t stream)
{
    const float* x     = (const float*)d_in[0];
    const float* Wk    = (const float*)d_in[1];
    const float* Wq    = (const float*)d_in[2];
    const float* Wv    = (const float*)d_in[3];
    const float* Wconv = (const float*)d_in[4];
    const float* ln1w  = (const float*)d_in[5];
    const float* ln1b  = (const float*)d_in[6];
    const float* ln2w  = (const float*)d_in[7];
    const float* ln2b  = (const float*)d_in[8];
    const float* W1    = (const float*)d_in[9];
    const float* b1    = (const float*)d_in[10];
    const float* W2    = (const float*)d_in[11];
    const float* b2    = (const float*)d_in[12];
    const float* Wc    = (const float*)d_in[13];
    const float* bc    = (const float*)d_in[14];
    float* out = (float*)d_out;

    const size_t MPE = (size_t)MP * EQ;

    float* w = (float*)d_ws;
    float* bh    = w; w += MPE;
    float* res1  = w; w += MPE;
    float* logit = w; w += (size_t)BQ * CQ;
    unsigned short* qpk  = (unsigned short*)w;
    unsigned short* kpk  = qpk + QPK_TOT;
    unsigned short* vbuf = kpk + QPK_TOT;
    unsigned short* actb = vbuf + MPE;              // packed activations
    unsigned short* ffh  = actb + MPE;              // packed FF hidden (MP x FQ)
    unsigned short* wbuf = ffh + (size_t)MP * FQ;

    const size_t WQKV = (size_t)EQ * EQ;
    unsigned short* WqT  = wbuf;
    unsigned short* WkT  = wbuf + WQKV;
    unsigned short* WvT  = wbuf + 2 * WQKV;
    unsigned short* WcvT = wbuf;                    // phase B overlays
    unsigned short* W1T  = wbuf + WQKV;
    unsigned short* W2T  = W1T + (size_t)EQ * FQ;

    copy_pad<<<BSQ, 256, 0, stream>>>(x, bh);

    for (int l = 0; l < LQ; ++l) {
        tconv_pk<<<dim3(12, 1, HQ), 256, 0, stream>>>(Wq + (size_t)l * HQ * EQ * DHQ, WqT, EQ, DHQ, 24, (size_t)EQ * DHQ, 4);
        tconv_pk<<<dim3(12, 1, HQ), 256, 0, stream>>>(Wk + (size_t)l * HQ * EQ * DHQ, WkT, EQ, DHQ, 24, (size_t)EQ * DHQ, 4);
        tconv_pk<<<dim3(12, 1, HQ), 256, 0, stream>>>(Wv + (size_t)l * HQ * EQ * DHQ, WvT, EQ, DHQ, 24, (size_t)EQ * DHQ, 4);

        ln_kernel<<<MP, 256, 0, stream>>>(bh, ln1w + l * EQ, ln1b + l * EQ, (__hip_bfloat16*)actb);

        mgemm_qkv<<<8 * 7 * 18, 256, 0, stream>>>(actb, wbuf, qpk, kpk, vbuf);

        tconv_pk<<<dim3(12, 12, 1), 256, 0, stream>>>(Wconv + (size_t)l * EQ * EQ, WcvT, EQ, EQ, 24, 0, 0);
        tconv_pk<<<dim3(12, 32, 1), 256, 0, stream>>>(W1 + (size_t)l * EQ * FQ, W1T, EQ, FQ, 24, 0, 0);
        tconv_pk<<<dim3(32, 12, 1), 256, 0, stream>>>(W2 + (size_t)l * FQ * EQ, W2T, FQ, EQ, 64, 0, 0);

        attn_fused<<<dim3(4, BQ * HQ), 256, 0, stream>>>(qpk, kpk, vbuf, actb);

        mgemm_pk<EPI_RES, 24, 2><<<8 * 13 * 6, 256, 0, stream>>>(
            actb, WcvT, res1, nullptr, bh, EQ, 6);

        ln_kernel<<<MP, 256, 0, stream>>>(res1, ln2w + l * EQ, ln2b + l * EQ, (__hip_bfloat16*)actb);

        mgemm_pk<EPI_BIAS_GELU, 24, 4><<<8 * 7 * 16, 256, 0, stream>>>(
            actb, W1T, ffh, b1 + l * FQ, nullptr, FQ, 16);
        mgemm_pk<EPI_BIAS_RES, 64, 2><<<8 * 13 * 6, 256, 0, stream>>>(
            ffh, W2T, bh, b2 + l * EQ, res1, EQ, 6);
    }
    logits_kernel<<<dim3(32, BQ), 256, 0, stream>>>(bh, Wc, bc, logit);
    smax_kernel<<<BQ, 256, 0, stream>>>(logit, out);
}

// Round 12
// 1100.906 us; speedup vs baseline: 1.9928x; 1.0318x over previous
//
#include <hip/hip_runtime.h>
#include <hip/hip_bf16.h>
#include <math.h>

#define BQ 32
#define SQ 197
#define EQ 768
#define HQ 12
#define DHQ 64
#define FQ 2048
#define LQ 4
#define CQ 1000
#define BSQ (BQ*SQ)     // 6304
#define SP 208          // padded rows per batch (13 * 16)
#define S16 13          // 16-row tiles per batch
#define MP (BQ*SP)      // 6656 padded total rows
#define QKV3 2304
#define KTP 7           // t-chunks of 32 (224) for P / V
#define LN_EPS 1e-5f

typedef __bf16 bf16x8 __attribute__((ext_vector_type(8)));
typedef float f32x4 __attribute__((ext_vector_type(4)));
typedef unsigned short u16x8 __attribute__((ext_vector_type(8)));

__device__ __forceinline__ __hip_bfloat16 tobf(float f) { return __float2bfloat16(f); }

// Packed fragment layout: chunk of 8 bf16 for (row-tile rt, k-tile kt, lane):
//   buf[pk(rt,KT,kt,lane)+e] <-> A[rt*16+(lane&15)][kt*32+(lane>>4)*8+e]
__device__ __forceinline__ size_t pk(int rt, int KT, int kt, int lane) {
    return (((size_t)rt * KT + kt) * 64 + (size_t)lane) * 8;
}

// sizes (elems)
#define QPK_SLAB (S16*2*512)            // per (b,h): 13 rt x 2 kt x 512
#define QPK_TOT  ((size_t)BQ*HQ*QPK_SLAB + 4096)
#define VPK_SLAB (4*KTP*512)            // per (b,h): 4 dt x 7 tt x 512
#define VPK_TOT  ((size_t)BQ*HQ*VPK_SLAB + 4096)

// ---------------- copy x into padded residual stream ------------------------
__global__ __launch_bounds__(256) void copy_pad(const float* __restrict__ x,
    float* __restrict__ bh)
{
    int r = blockIdx.x;
    int b = r / SQ, s = r % SQ;
    const float* src = x + (size_t)r * EQ;
    float* dst = bh + ((size_t)b * SP + s) * EQ;
    int t = threadIdx.x;
    dst[t] = src[t];
    dst[t + 256] = src[t + 256];
    dst[t + 512] = src[t + 512];
}

// ---------------- transpose + convert + PACK weights ------------------------
__global__ __launch_bounds__(256) void tconv_pk(const float* __restrict__ in,
    unsigned short* __restrict__ out, int R, int C, int KT, size_t slab, int ntPerSlab)
{
    __shared__ float tile[64][65];
    const float* ip = in + (size_t)blockIdx.z * slab;
    int r0 = blockIdx.x * 64, c0 = blockIdx.y * 64;
    int t = threadIdx.x;
    int tc = t & 63, tr = t >> 6;
    #pragma unroll
    for (int p = 0; p < 16; ++p) {
        int r = p * 4 + tr;
        tile[r][tc] = ip[(size_t)(r0 + r) * C + c0 + tc];
    }
    __syncthreads();
    int ntb = blockIdx.z * ntPerSlab + (c0 >> 4);
    int ktb = r0 >> 5;
    #pragma unroll
    for (int p = 0; p < 2; ++p) {
        int cc = p * 256 + t;
        int lane = cc & 63, grp = cc >> 6;
        int ktl = grp & 1, ntl = grp >> 1;
        int er = ktl * 32 + (lane >> 4) * 8;
        int dc = ntl * 16 + (lane & 15);
        u16x8 v;
        #pragma unroll
        for (int e = 0; e < 8; ++e) {
            __hip_bfloat16 h = tobf(tile[er + e][dc]);
            v[e] = *(unsigned short*)&h;
        }
        *(u16x8*)(out + pk(ntb + ntl, KT, ktb + ktl, lane)) = v;
    }
}

// ---------------- LayerNorm: fp32 (padded rows) -> PACKED bf16 (KT=24) ------
__global__ __launch_bounds__(256) void ln_kernel(const float* __restrict__ in,
    const float* __restrict__ w, const float* __restrict__ b,
    __hip_bfloat16* __restrict__ out)
{
    int row = blockIdx.x;
    const float* x = in + (size_t)row * EQ;
    int t = threadIdx.x;
    float v0 = x[t];
    float v1 = x[t + 256];
    float v2 = x[t + 512];
    __shared__ float red[256];
    red[t] = v0 + v1 + v2;
    __syncthreads();
    for (int off = 128; off > 0; off >>= 1) {
        if (t < off) red[t] += red[t + off];
        __syncthreads();
    }
    float mu = red[0] * (1.0f / EQ);
    __syncthreads();
    float d0 = v0 - mu, d1 = v1 - mu, d2 = v2 - mu;
    red[t] = d0*d0 + d1*d1 + d2*d2;
    __syncthreads();
    for (int off = 128; off > 0; off >>= 1) {
        if (t < off) red[t] += red[t + off];
        __syncthreads();
    }
    float rs = rsqrtf(red[0] * (1.0f / EQ) + LN_EPS);
    int rt = row >> 4, rsl = row & 15;
    float n0 = d0 * rs * w[t]       + b[t];
    float n1 = d1 * rs * w[t + 256] + b[t + 256];
    float n2 = d2 * rs * w[t + 512] + b[t + 512];
    #pragma unroll
    for (int p = 0; p < 3; ++p) {
        int k = t + (p << 8);
        float val = p == 0 ? n0 : (p == 1 ? n1 : n2);
        int kt = k >> 5, lane = (((k >> 3) & 3) << 4) + rsl, e = k & 7;
        out[pk(rt, 24, kt, lane) + e] = tobf(val);
    }
}

// ---------------- packed MFMA GEMM core (no barriers in K-loop) -------------
enum { EPI_NONE = 0, EPI_RES = 1, EPI_BIAS_GELU = 2, EPI_BIAS_RES = 3 };

template<int EPI, int KT, int RT>
__global__ __launch_bounds__(256) void mgemm_pk(
    const unsigned short* __restrict__ Apk, const unsigned short* __restrict__ Bpk,
    void* __restrict__ Cm, const float* __restrict__ bias,
    const float* __restrict__ res, int N, int nNT)
{
    const int nRowT = (RT == 4) ? 52 : 104;        // MP/(RT*32)
    const int g = blockIdx.x & 7;
    const int sIdx = blockIdx.x >> 3;
    const int b0 = (nRowT * g) >> 3, b1 = (nRowT * (g + 1)) >> 3;
    const int colT = sIdx % nNT, rloc = sIdx / nNT;
    if (b0 + rloc >= b1) return;
    const int row0 = (b0 + rloc) * (RT * 32), col0 = colT << 7;

    const int tid = threadIdx.x;
    const int lane = tid & 63;
    const int w = tid >> 6;
    const int wr = w >> 1, wc = w & 1;
    const int l15 = lane & 15, quad = lane >> 4;
    const int rt0 = (row0 >> 4) + wr * RT;
    const int nt0 = (col0 >> 4) + wc * 4;

    f32x4 acc[RT][4] = {};
    bf16x8 a[2][RT], b[2][4];
    auto ld = [&](int buf, int kt) {
        #pragma unroll
        for (int i = 0; i < RT; ++i)
            a[buf][i] = *(const bf16x8*)(Apk + pk(rt0 + i, KT, kt, lane));
        #pragma unroll
        for (int j = 0; j < 4; ++j)
            b[buf][j] = *(const bf16x8*)(Bpk + pk(nt0 + j, KT, kt, lane));
    };
    ld(0, 0);
    #pragma unroll 2
    for (int kt = 0; kt < KT; ++kt) {
        int cur = kt & 1;
        if (kt + 1 < KT) ld(cur ^ 1, kt + 1);
        #pragma unroll
        for (int i = 0; i < RT; ++i)
            #pragma unroll
            for (int j = 0; j < 4; ++j)
                acc[i][j] = __builtin_amdgcn_mfma_f32_16x16x32_bf16(a[cur][i], b[cur][j], acc[i][j], 0, 0, 0);
    }

    if constexpr (EPI == EPI_BIAS_GELU) {
        __shared__ unsigned short Cs[128][136];
        #pragma unroll
        for (int j = 0; j < 4; ++j) {
            float bv = bias[col0 + wc * 64 + j * 16 + l15];
            #pragma unroll
            for (int i = 0; i < RT; ++i)
                #pragma unroll
                for (int rg = 0; rg < 4; ++rg) {
                    float v = acc[i][j][rg] + bv;
                    v = 0.5f * v * (1.0f + erff(v * 0.70710678118654752f));
                    __hip_bfloat16 h = tobf(v);
                    Cs[wr * 64 + i * 16 + quad * 4 + rg][wc * 64 + j * 16 + l15] =
                        *(unsigned short*)&h;
                }
        }
        __syncthreads();
        const int KT2 = N >> 5;
        #pragma unroll
        for (int p = 0; p < 8; ++p) {
            int cc = p * 256 + tid;
            int ln2 = cc & 63, grp = cc >> 6;
            int ktl = grp & 3, rtl = grp >> 2;
            int rowl = rtl * 16 + (ln2 & 15);
            u16x8 v;
            #pragma unroll
            for (int e = 0; e < 8; ++e)
                v[e] = Cs[rowl][ktl * 32 + (ln2 >> 4) * 8 + e];
            *(u16x8*)((unsigned short*)Cm + pk((row0 >> 4) + rtl, KT2, (col0 >> 5) + ktl, ln2)) = v;
        }
    } else {
        #pragma unroll
        for (int j = 0; j < 4; ++j) {
            int c = col0 + wc * 64 + j * 16 + l15;
            float bv = (EPI == EPI_BIAS_RES) ? bias[c] : 0.f;
            #pragma unroll
            for (int i = 0; i < RT; ++i)
                #pragma unroll
                for (int rg = 0; rg < 4; ++rg) {
                    int r = row0 + wr * (RT * 16) + i * 16 + quad * 4 + rg;
                    float v = acc[i][j][rg];
                    size_t idx = (size_t)r * N + c;
                    if (EPI == EPI_BIAS_RES) {
                        ((float*)Cm)[idx] = v + bv + res[idx];
                    } else if (EPI == EPI_RES) {
                        ((float*)Cm)[idx] = v + res[idx];
                    } else {
                        ((__hip_bfloat16*)Cm)[idx] = tobf(v);
                    }
                }
        }
    }
}

// ---------------- QKV GEMM: packed A/B -> per-head q/k pk + V in PV-B pk ----
__global__ __launch_bounds__(256) void mgemm_qkv(
    const unsigned short* __restrict__ Apk, const unsigned short* __restrict__ Bpk,
    unsigned short* __restrict__ qpk, unsigned short* __restrict__ kpk,
    unsigned short* __restrict__ vpk)
{
    const int g = blockIdx.x & 7;
    const int sIdx = blockIdx.x >> 3;
    const int b0 = (52 * g) >> 3, b1 = (52 * (g + 1)) >> 3;
    const int colT = sIdx % 18, rloc = sIdx / 18;
    if (b0 + rloc >= b1) return;
    const int row0 = (b0 + rloc) << 7, col0 = colT << 7;

    const int tid = threadIdx.x;
    const int lane = tid & 63;
    const int w = tid >> 6;
    const int wr = w >> 1, wc = w & 1;
    const int l15 = lane & 15, quad = lane >> 4;
    const int rt0 = (row0 >> 4) + wr * 4;
    const int nt0 = (col0 >> 4) + wc * 4;

    f32x4 acc[4][4] = {};
    bf16x8 a[2][4], b[2][4];
    auto ld = [&](int buf, int kt) {
        #pragma unroll
        for (int i = 0; i < 4; ++i)
            a[buf][i] = *(const bf16x8*)(Apk + pk(rt0 + i, 24, kt, lane));
        #pragma unroll
        for (int j = 0; j < 4; ++j)
            b[buf][j] = *(const bf16x8*)(Bpk + pk(nt0 + j, 24, kt, lane));
    };
    ld(0, 0);
    #pragma unroll 2
    for (int kt = 0; kt < 24; ++kt) {
        int cur = kt & 1;
        if (kt + 1 < 24) ld(cur ^ 1, kt + 1);
        #pragma unroll
        for (int i = 0; i < 4; ++i)
            #pragma unroll
            for (int j = 0; j < 4; ++j)
                acc[i][j] = __builtin_amdgcn_mfma_f32_16x16x32_bf16(a[cur][i], b[cur][j], acc[i][j], 0, 0, 0);
    }

    __shared__ unsigned short Cs[128][136];
    #pragma unroll
    for (int j = 0; j < 4; ++j)
        #pragma unroll
        for (int i = 0; i < 4; ++i)
            #pragma unroll
            for (int rg = 0; rg < 4; ++rg) {
                __hip_bfloat16 h = tobf(acc[i][j][rg]);
                Cs[wr * 64 + i * 16 + quad * 4 + rg][wc * 64 + j * 16 + l15] =
                    *(unsigned short*)&h;
            }
    __syncthreads();

    const int treg = col0 >> 7;   // 0..5 q, 6..11 k, 12..17 v
    if (treg < 12) {
        unsigned short* dst = (treg < 6) ? qpk : kpk;
        const int h0 = ((col0 % 768) >> 6);
        #pragma unroll
        for (int p = 0; p < 8; ++p) {
            int cc = p * 256 + tid;
            int ln2 = cc & 63, grp = cc >> 6;
            int hl = grp & 1, kt = (grp >> 1) & 1, rtl = grp >> 2;
            int row16 = (row0 >> 4) + rtl;
            int bb = row16 / S16;
            int s16 = row16 - bb * S16;
            int h = h0 + hl;
            u16x8 v;
            #pragma unroll
            for (int e = 0; e < 8; ++e)
                v[e] = Cs[rtl * 16 + (ln2 & 15)][hl * 64 + kt * 32 + (ln2 >> 4) * 8 + e];
            *(u16x8*)(dst + ((((size_t)(bb * HQ + h) * S16 + s16) * 2 + kt) << 9) + ln2 * 8) = v;
        }
    } else {
        // V -> PV-B-fragment packed slabs per (b,h).
        // Per-instruction Cs reads are ROW-contiguous (64 consecutive dloc) ->
        // conflict-free; writes are 4x256B coalesced segments.
        const int h0 = (col0 - 1536) >> 6;     // block covers heads h0, h0+1
        #pragma unroll
        for (int p = 0; p < 8; ++p) {
            int cc = p * 256 + tid;
            int dloc = cc & 127;               // (w&1)*64 + lane : contiguous
            int g8 = cc >> 7;                  // 0..15, constant per wave
            int gr = row0 + g8 * 8;            // global row of this 8-run
            int bb = gr / SP;
            int tl = gr - bb * SP;             // 0..200, 8-aligned
            int tt = tl >> 5;
            int tsub = (tl >> 3) & 3;
            int h = h0 + (dloc >> 6);
            int dt = (dloc >> 4) & 3;
            int lane2 = tsub * 16 + (dloc & 15);
            u16x8 v;
            #pragma unroll
            for (int e = 0; e < 8; ++e)
                v[e] = Cs[g8 * 8 + e][dloc];
            *(u16x8*)(vpk + (size_t)(bb * HQ + h) * VPK_SLAB + pk(dt, KTP, tt, lane2)) = v;
        }
    }
}

// ------------- FUSED attention: QK^T+softmax -> P in LDS -> P@V -> o pk -----
// V read as packed B-fragments straight from global (coalesced 1KB chunks).
// Ps columns XOR-swizzled by row bit3 to kill 4-way write conflicts.
__global__ __launch_bounds__(256) void attn_fused(
    const unsigned short* __restrict__ qpk, const unsigned short* __restrict__ kpk,
    const unsigned short* __restrict__ vpk, unsigned short* __restrict__ opk)
{
    __shared__ float redm[4][64], reds[4][64];
    __shared__ unsigned short Ps[64][264];
    __shared__ unsigned short Cs[64][72];
    const int s0 = blockIdx.x * 64;
    const int bh = blockIdx.y;
    const int b = bh / HQ, h = bh % HQ;
    const int tid = threadIdx.x;
    const int w = tid >> 6, lane = tid & 63;
    const int wr = w >> 1, wc = w & 1;
    const int l15 = lane & 15, quad = lane >> 4;

    const unsigned short* qs = qpk + (size_t)bh * QPK_SLAB;
    const unsigned short* ks = kpk + (size_t)bh * QPK_SLAB;

    f32x4 acc[4][4] = {};
    #pragma unroll
    for (int kk = 0; kk < 2; ++kk) {
        bf16x8 af[4], bfr[4];
        #pragma unroll
        for (int i = 0; i < 4; ++i)
            af[i] = *(const bf16x8*)(qs + ((((s0 >> 4) + i) * 2 + kk) << 9) + lane * 8);
        #pragma unroll
        for (int j = 0; j < 4; ++j)
            bfr[j] = *(const bf16x8*)(ks + (((w * 4 + j) * 2 + kk) << 9) + lane * 8);
        #pragma unroll
        for (int i = 0; i < 4; ++i)
            #pragma unroll
            for (int j = 0; j < 4; ++j)
                acc[i][j] = __builtin_amdgcn_mfma_f32_16x16x32_bf16(af[i], bfr[j], acc[i][j], 0, 0, 0);
    }

    const float scale = 0.07124704998790965f;  // 1/sqrt(197)
    float sc[4][4][4];
    #pragma unroll
    for (int i = 0; i < 4; ++i)
        #pragma unroll
        for (int j = 0; j < 4; ++j) {
            bool ok = (w * 64 + j * 16 + l15) < SQ;
            #pragma unroll
            for (int rg = 0; rg < 4; ++rg)
                sc[i][rg][j] = ok ? acc[i][j][rg] * scale : -1e30f;
        }

    #pragma unroll
    for (int i = 0; i < 4; ++i)
        #pragma unroll
        for (int rg = 0; rg < 4; ++rg) {
            float m = fmaxf(fmaxf(sc[i][rg][0], sc[i][rg][1]), fmaxf(sc[i][rg][2], sc[i][rg][3]));
            #pragma unroll
            for (int d = 1; d < 16; d <<= 1) m = fmaxf(m, __shfl_xor(m, d));
            if (l15 == 0) redm[w][i * 16 + quad * 4 + rg] = m;
        }
    __syncthreads();

    float tot[4][4];
    #pragma unroll
    for (int i = 0; i < 4; ++i)
        #pragma unroll
        for (int rg = 0; rg < 4; ++rg) {
            int row = i * 16 + quad * 4 + rg;
            float m = fmaxf(fmaxf(redm[0][row], redm[1][row]),
                            fmaxf(redm[2][row], redm[3][row]));
            float s = 0.f;
            #pragma unroll
            for (int j = 0; j < 4; ++j) {
                float e = expf(sc[i][rg][j] - m);
                sc[i][rg][j] = e;
                s += e;
            }
            #pragma unroll
            for (int d = 1; d < 16; d <<= 1) s += __shfl_xor(s, d);
            if (l15 == 0) reds[w][row] = s;
            tot[i][rg] = 0.f;
        }
    __syncthreads();

    #pragma unroll
    for (int i = 0; i < 4; ++i)
        #pragma unroll
        for (int rg = 0; rg < 4; ++rg) {
            int row = i * 16 + quad * 4 + rg;
            tot[i][rg] = reds[0][row] + reds[1][row] + reds[2][row] + reds[3][row];
        }

    // normalized P -> LDS, columns XOR-swizzled by row bit3 (conflict-free)
    #pragma unroll
    for (int i = 0; i < 4; ++i)
        #pragma unroll
        for (int rg = 0; rg < 4; ++rg) {
            float inv = 1.0f / tot[i][rg];
            int xr = (quad >> 1) << 4;          // ((row>>3)&1)<<4
            #pragma unroll
            for (int j = 0; j < 4; ++j) {
                __hip_bfloat16 hv = tobf(sc[i][rg][j] * inv);
                Ps[i * 16 + quad * 4 + rg][(w * 64 + j * 16 + l15) ^ xr] = *(unsigned short*)&hv;
            }
        }
    __syncthreads();

    // P @ V : A-frags from Ps (XOR read), B-frags from vpk global (coalesced)
    const unsigned short* vs = vpk + (size_t)bh * VPK_SLAB;
    f32x4 av[2][2] = {};
    bf16x8 vb[2][2];
    #pragma unroll
    for (int j = 0; j < 2; ++j)
        vb[0][j] = *(const bf16x8*)(vs + pk(wc * 2 + j, KTP, 0, lane));
    #pragma unroll
    for (int kk = 0; kk < KTP; ++kk) {
        int cur = kk & 1;
        if (kk + 1 < KTP) {
            #pragma unroll
            for (int j = 0; j < 2; ++j)
                vb[cur ^ 1][j] = *(const bf16x8*)(vs + pk(wc * 2 + j, KTP, kk + 1, lane));
        }
        bf16x8 af[2];
        #pragma unroll
        for (int i = 0; i < 2; ++i) {
            int row = wr * 32 + i * 16 + l15;
            int col = (kk * 32 + quad * 8) ^ (((l15 >> 3) & 1) << 4);
            af[i] = *(const bf16x8*)&Ps[row][col];
        }
        #pragma unroll
        for (int i = 0; i < 2; ++i)
            #pragma unroll
            for (int j = 0; j < 2; ++j)
                av[i][j] = __builtin_amdgcn_mfma_f32_16x16x32_bf16(af[i], vb[cur][j], av[i][j], 0, 0, 0);
    }

    #pragma unroll
    for (int i = 0; i < 2; ++i)
        #pragma unroll
        for (int j = 0; j < 2; ++j)
            #pragma unroll
            for (int rg = 0; rg < 4; ++rg) {
                __hip_bfloat16 hv = tobf(av[i][j][rg]);
                Cs[wr * 32 + i * 16 + quad * 4 + rg][wc * 32 + j * 16 + l15] =
                    *(unsigned short*)&hv;
            }
    __syncthreads();

    const int rt0 = b * S16 + (s0 >> 4);
    const int kt0 = h * 2;
    int validRt = (SP - s0) >> 4; if (validRt > 4) validRt = 4;
    #pragma unroll
    for (int p = 0; p < 2; ++p) {
        int cc = p * 256 + tid;
        int ln2 = cc & 63, grp = cc >> 6;
        int ktl = grp & 1, rtl = grp >> 1;
        if (rtl < validRt) {
            int rowl = rtl * 16 + (ln2 & 15);
            int colb = ktl * 32 + (ln2 >> 4) * 8;
            u16x8 v;
            #pragma unroll
            for (int e = 0; e < 8; ++e)
                v[e] = Cs[rowl][colb + e];
            *(u16x8*)(opk + pk(rt0 + rtl, 24, kt0 + ktl, ln2)) = v;
        }
    }
}

// ---------------- classifier: split-K logits + softmax ----------------------
__global__ __launch_bounds__(256) void logits_kernel(
    const float* __restrict__ hbuf, const float* __restrict__ Wc,
    const float* __restrict__ bc, float* __restrict__ logits)
{
    __shared__ __align__(16) float hs[768];
    __shared__ float red[256];
    int b = blockIdx.y;
    int tid = threadIdx.x;
    const float* hr = hbuf + (size_t)b * SP * EQ;   // s=0 row
    for (int p = tid; p < 192; p += 256)
        *(float4*)&hs[p << 2] = *(const float4*)(hr + (p << 2));
    __syncthreads();
    int cl = tid & 31, ks = tid >> 5;
    int c = blockIdx.x * 32 + cl;
    int cs = (c < CQ) ? c : 0;
    float s = 0.f;
    int e0 = ks * 96;
    #pragma unroll 8
    for (int e = 0; e < 96; ++e)
        s = fmaf(hs[e0 + e], Wc[(size_t)(e0 + e) * CQ + cs], s);
    red[tid] = s;
    __syncthreads();
    for (int off = 128; off >= 32; off >>= 1) {
        if (tid < off) red[tid] += red[tid + off];
        __syncthreads();
    }
    if (tid < 32 && c < CQ)
        logits[(size_t)b * CQ + c] = red[tid] + bc[c];
}

__global__ __launch_bounds__(256) void smax_kernel(
    const float* __restrict__ logits, float* __restrict__ out)
{
    __shared__ float red[256];
    int b = blockIdx.x;
    int t = threadIdx.x;
    const float* lp = logits + (size_t)b * CQ;
    float lg[4];
    #pragma unroll
    for (int j = 0; j < 4; ++j) {
        int c = t + j * 256;
        lg[j] = (c < CQ) ? lp[c] : -1e30f;
    }
    float m = fmaxf(fmaxf(lg[0], lg[1]), fmaxf(lg[2], lg[3]));
    red[t] = m;
    __syncthreads();
    for (int off = 128; off; off >>= 1) {
        if (t < off) red[t] = fmaxf(red[t], red[t + off]);
        __syncthreads();
    }
    m = red[0];
    __syncthreads();
    float ex[4], s = 0.f;
    #pragma unroll
    for (int j = 0; j < 4; ++j) {
        ex[j] = (t + j * 256 < CQ) ? expf(lg[j] - m) : 0.f;
        s += ex[j];
    }
    red[t] = s;
    __syncthreads();
    for (int off = 128; off; off >>= 1) {
        if (t < off) red[t] += red[t + off];
        __syncthreads();
    }
    float inv = 1.0f / red[0];
    #pragma unroll
    for (int j = 0; j < 4; ++j)
        if (t + j * 256 < CQ) out[(size_t)b * CQ + t + j * 256] = ex[j] * inv;
}

extern "C" void kernel_launch(void* const* d_in, const int* in_sizes, int n_in,
                              void* d_out, int out_size, void* d_ws, size_t ws_size,
                              hipStream_t stream)
{
    const float* x     = (const float*)d_in[0];
    const float* Wk    = (const float*)d_in[1];
    const float* Wq    = (const float*)d_in[2];
    const float* Wv    = (const float*)d_in[3];
    const float* Wconv = (const float*)d_in[4];
    const float* ln1w  = (const float*)d_in[5];
    const float* ln1b  = (const float*)d_in[6];
    const float* ln2w  = (const float*)d_in[7];
    const float* ln2b  = (const float*)d_in[8];
    const float* W1    = (const float*)d_in[9];
    const float* b1    = (const float*)d_in[10];
    const float* W2    = (const float*)d_in[11];
    const float* b2    = (const float*)d_in[12];
    const float* Wc    = (const float*)d_in[13];
    const float* bc    = (const float*)d_in[14];
    float* out = (float*)d_out;

    const size_t MPE = (size_t)MP * EQ;

    float* w = (float*)d_ws;
    float* bh    = w; w += MPE;
    float* res1  = w; w += MPE;
    float* logit = w; w += (size_t)BQ * CQ;
    unsigned short* qpk  = (unsigned short*)w;
    unsigned short* kpk  = qpk + QPK_TOT;
    unsigned short* vpk  = kpk + QPK_TOT;
    unsigned short* actb = vpk + VPK_TOT;           // packed activations
    unsigned short* ffh  = actb + MPE;              // packed FF hidden (MP x FQ)
    unsigned short* wbuf = ffh + (size_t)MP * FQ;

    const size_t WQKV = (size_t)EQ * EQ;
    unsigned short* WqT  = wbuf;
    unsigned short* WkT  = wbuf + WQKV;
    unsigned short* WvT  = wbuf + 2 * WQKV;
    unsigned short* WcvT = wbuf;                    // phase B overlays
    unsigned short* W1T  = wbuf + WQKV;
    unsigned short* W2T  = W1T + (size_t)EQ * FQ;

    copy_pad<<<BSQ, 256, 0, stream>>>(x, bh);

    for (int l = 0; l < LQ; ++l) {
        tconv_pk<<<dim3(12, 1, HQ), 256, 0, stream>>>(Wq + (size_t)l * HQ * EQ * DHQ, WqT, EQ, DHQ, 24, (size_t)EQ * DHQ, 4);
        tconv_pk<<<dim3(12, 1, HQ), 256, 0, stream>>>(Wk + (size_t)l * HQ * EQ * DHQ, WkT, EQ, DHQ, 24, (size_t)EQ * DHQ, 4);
        tconv_pk<<<dim3(12, 1, HQ), 256, 0, stream>>>(Wv + (size_t)l * HQ * EQ * DHQ, WvT, EQ, DHQ, 24, (size_t)EQ * DHQ, 4);

        ln_kernel<<<MP, 256, 0, stream>>>(bh, ln1w + l * EQ, ln1b + l * EQ, (__hip_bfloat16*)actb);

        mgemm_qkv<<<8 * 7 * 18, 256, 0, stream>>>(actb, wbuf, qpk, kpk, vpk);

        tconv_pk<<<dim3(12, 12, 1), 256, 0, stream>>>(Wconv + (size_t)l * EQ * EQ, WcvT, EQ, EQ, 24, 0, 0);
        tconv_pk<<<dim3(12, 32, 1), 256, 0, stream>>>(W1 + (size_t)l * EQ * FQ, W1T, EQ, FQ, 24, 0, 0);
        tconv_pk<<<dim3(32, 12, 1), 256, 0, stream>>>(W2 + (size_t)l * FQ * EQ, W2T, FQ, EQ, 64, 0, 0);

        attn_fused<<<dim3(4, BQ * HQ), 256, 0, stream>>>(qpk, kpk, vpk, actb);

        mgemm_pk<EPI_RES, 24, 2><<<8 * 13 * 6, 256, 0, stream>>>(
            actb, WcvT, res1, nullptr, bh, EQ, 6);

        ln_kernel<<<MP, 256, 0, stream>>>(res1, ln2w + l * EQ, ln2b + l * EQ, (__hip_bfloat16*)actb);

        mgemm_pk<EPI_BIAS_GELU, 24, 4><<<8 * 7 * 16, 256, 0, stream>>>(
            actb, W1T, ffh, b1 + l * FQ, nullptr, FQ, 16);
        mgemm_pk<EPI_BIAS_RES, 64, 2><<<8 * 13 * 6, 256, 0, stream>>>(
            ffh, W2T, bh, b2 + l * EQ, res1, EQ, 6);
    }
    logits_kernel<<<dim3(32, BQ), 256, 0, stream>>>(bh, Wc, bc, logit);
    smax_kernel<<<BQ, 256, 0, stream>>>(logit, out);
}